// Round 16
// baseline (214.990 us; speedup 1.0000x reference)
//
#include <hip/hip_runtime.h>
#include <hip/hip_bf16.h>
#include <math.h>

typedef short bf16x8 __attribute__((ext_vector_type(8)));
typedef float f32x4  __attribute__((ext_vector_type(4)));
#define MFMA16(a,b,c) __builtin_amdgcn_mfma_f32_16x16x32_bf16(a,b,c,0,0,0)

#define EPSF 1e-5f
#define QSC 0.18033688f   // 0.125 * log2(e), folded into Q

#if __has_builtin(__builtin_amdgcn_exp2f)
#define EXP2(x) __builtin_amdgcn_exp2f(x)
#else
#define EXP2(x) exp2f(x)
#endif

__device__ __forceinline__ unsigned int pk2n(float a, float b){
  __hip_bfloat162 h = __float22bfloat162_rn(make_float2(a, b));
  return *reinterpret_cast<unsigned int*>(&h);
}
__device__ __forceinline__ unsigned short bfn(float f){
  __hip_bfloat16 h = __float2bfloat16(f);
  return *reinterpret_cast<unsigned short*>(&h);
}
__device__ __forceinline__ float4 ld4(const float* p){ return *reinterpret_cast<const float4*>(p); }

// async global->LDS, 16B per lane; LDS dest = wave-uniform base + lane*16
__device__ __forceinline__ void gl_lds16(const unsigned short* g, unsigned short* l){
  __builtin_amdgcn_global_load_lds(
      (const __attribute__((address_space(1))) unsigned int*)g,
      (__attribute__((address_space(3))) unsigned int*)l, 16, 0, 0);
}

// ---------------- preamble: fused GroupNorm (blocks 0..127) + weight cvt (blocks 128..383) ----------------
__global__ __launch_bounds__(512) void pre_k(const float* __restrict__ x,
                                             const float* __restrict__ gnw,
                                             const float* __restrict__ gnb,
                                             unsigned short* __restrict__ xnT,
                                             const float* __restrict__ qkvw,
                                             const float* __restrict__ projw,
                                             unsigned int* __restrict__ wqb,
                                             unsigned int* __restrict__ wpb){
  __shared__ float Xl[2][64*65];
  __shared__ float red[16];
  int blk = blockIdx.x;
  int tid = threadIdx.x;
  if(blk >= 128){
    const float* src; unsigned int* dst; int base;
    if(blk < 320){ src = qkvw; dst = wqb; base = 128; }
    else         { src = projw; dst = wpb; base = 320; }
    int i = (blk - base)*1024 + tid*2;
    #pragma unroll
    for(int j = 0; j < 2; j++){
      float4 v = reinterpret_cast<const float4*>(src)[i + j];
      uint2 r; r.x = pk2n(v.x, v.y); r.y = pk2n(v.z, v.w);
      reinterpret_cast<uint2*>(dst)[i + j] = r;
    }
    return;
  }
  int b = blk >> 3, g = blk & 7;
  const float4* p4 = reinterpret_cast<const float4*>(x + (size_t)blk * 65536);
  float s1 = 0.f, s2 = 0.f;
  for(int i = tid; i < 16384; i += 512){
    float4 v = p4[i];
    s1 += (v.x + v.y) + (v.z + v.w);
    s2 += v.x*v.x + v.y*v.y + v.z*v.z + v.w*v.w;
  }
  #pragma unroll
  for(int off = 32; off; off >>= 1){ s1 += __shfl_xor(s1, off); s2 += __shfl_xor(s2, off); }
  if((tid & 63) == 0){ red[tid >> 6] = s1; red[8 + (tid >> 6)] = s2; }
  __syncthreads();
  float a = 0.f, b2 = 0.f;
  #pragma unroll
  for(int w = 0; w < 8; w++){ a += red[w]; b2 += red[8 + w]; }
  float mean = a * (1.f / 65536.f);
  float rstd = rsqrtf(b2 * (1.f / 65536.f) - mean * mean + EPSF);
  int half = tid >> 8, t256 = tid & 255;
  int nq = t256 & 15, rr = t256 >> 4;
  int c0 = g * 64;
  for(int it = 0; it < 8; it++){
    int n0 = (it*2 + half) * 64;
    __syncthreads();
    #pragma unroll
    for(int p = 0; p < 4; p++){
      int cl = p * 16 + rr, c = c0 + cl;
      float s = rstd * gnw[c], t = gnb[c] - mean * s;
      float4 v = ld4(x + ((size_t)(b*512 + c))*1024 + n0 + 4*nq);
      Xl[half][(4*nq+0)*65 + cl] = v.x*s + t;
      Xl[half][(4*nq+1)*65 + cl] = v.y*s + t;
      Xl[half][(4*nq+2)*65 + cl] = v.z*s + t;
      Xl[half][(4*nq+3)*65 + cl] = v.w*s + t;
    }
    __syncthreads();
    int n = t256 >> 2, cq = t256 & 3;
    float f[16];
    #pragma unroll
    for(int k = 0; k < 16; k++) f[k] = Xl[half][n*65 + 16*cq + k];
    uint4 w0, w1;
    w0.x = pk2n(f[0],f[1]);  w0.y = pk2n(f[2],f[3]);  w0.z = pk2n(f[4],f[5]);  w0.w = pk2n(f[6],f[7]);
    w1.x = pk2n(f[8],f[9]);  w1.y = pk2n(f[10],f[11]);w1.z = pk2n(f[12],f[13]);w1.w = pk2n(f[14],f[15]);
    unsigned short* dp = xnT + ((size_t)(b*1024 + n0 + n))*512 + c0 + 16*cq;
    *reinterpret_cast<uint4*>(dp)     = w0;
    *reinterpret_cast<uint4*>(dp + 8) = w1;
  }
}

// ---- GEMM core: BK=64 DOUBLE-buffered, counted vmcnt(8) + raw s_barrier (T4),
// gl_lds staging, XOR-swizzled linear LDS (r15 measured-best). ----

// ---------------- QKV GEMM: Q,K transposed (Q pre-scaled) + V natural ----------------
__global__ __launch_bounds__(256) void qkv_mm(const unsigned short* __restrict__ A,
                                              const unsigned short* __restrict__ Bx,
                                              const float* __restrict__ bias,
                                              unsigned short* __restrict__ T,
                                              unsigned short* __restrict__ V){
  __shared__ __align__(16) unsigned short As[2][128*64], Bs[2][128*64];
  int tid = threadIdx.x;
  int n0 = blockIdx.x*128, o0 = blockIdx.y*128, b = blockIdx.z;
  int wid = tid >> 6, wr = wid >> 1, wc = wid & 1, ln = tid & 15, g = (tid >> 4) & 3;
  int l = tid & 63;
  int rsw = (ln & 7) << 3;
  int srow = 32*wid + (l >> 3);
  int scol = (((l & 7) ^ (l >> 3)) << 3);
  const unsigned short* Ag = A  + (size_t)(o0 + srow)*512 + scol;
  const unsigned short* Bg = Bx + ((size_t)(b*1024 + n0 + srow))*512 + scol;
  f32x4 acc[4][4] = {};
  #pragma unroll
  for(int c = 0; c < 4; c++){
    gl_lds16(Ag + (size_t)(8*c)*512, &As[0][(32*wid + 8*c)*64]);
    gl_lds16(Bg + (size_t)(8*c)*512, &Bs[0][(32*wid + 8*c)*64]);
  }
  for(int t = 0; t < 8; t++){
    int buf = t & 1;
    if(t < 7){
      int k1 = (t + 1) * 64;
      #pragma unroll
      for(int c = 0; c < 4; c++){
        gl_lds16(Ag + (size_t)(8*c)*512 + k1, &As[buf^1][(32*wid + 8*c)*64]);
        gl_lds16(Bg + (size_t)(8*c)*512 + k1, &Bs[buf^1][(32*wid + 8*c)*64]);
      }
      asm volatile("s_waitcnt vmcnt(8)" ::: "memory");   // tile t's 8 loads done
    } else {
      asm volatile("s_waitcnt vmcnt(0)" ::: "memory");
    }
    __builtin_amdgcn_sched_barrier(0);
    __builtin_amdgcn_s_barrier();
    __builtin_amdgcn_sched_barrier(0);
    #pragma unroll
    for(int kh = 0; kh < 2; kh++){
      int ro = (kh*32 + 8*g) ^ rsw;
      bf16x8 af[4], bfv[4];
      #pragma unroll
      for(int mf = 0; mf < 4; mf++)
        af[mf] = *reinterpret_cast<const bf16x8*>(&As[buf][(wr*64 + 16*mf + ln)*64 + ro]);
      #pragma unroll
      for(int nf = 0; nf < 4; nf++)
        bfv[nf] = *reinterpret_cast<const bf16x8*>(&Bs[buf][(wc*64 + 16*nf + ln)*64 + ro]);
      #pragma unroll
      for(int mf = 0; mf < 4; mf++)
        #pragma unroll
        for(int nf = 0; nf < 4; nf++)
          acc[mf][nf] = MFMA16(af[mf], bfv[nf], acc[mf][nf]);
    }
    __builtin_amdgcn_sched_barrier(0);
    __builtin_amdgcn_s_barrier();
  }
  int obase = o0 + wr*64, nbase = n0 + wc*64;
  unsigned short* scr = &As[0][0] + wid * 2560;          // 64 rows x 40 pitch, per-wave scratch
  float sc = (obase < 512) ? QSC : 1.0f;
  if(obase < 1024){
    #pragma unroll
    for(int h2 = 0; h2 < 2; h2++){
      asm volatile("s_waitcnt lgkmcnt(0)" ::: "memory");
      __builtin_amdgcn_sched_barrier(0);
      #pragma unroll
      for(int mf2 = 0; mf2 < 2; mf2++){
        int mf = 2*h2 + mf2;
        int og = obase + 16*mf + 4*g;
        float b0 = bias[og], b1 = bias[og+1], b2 = bias[og+2], b3 = bias[og+3];
        #pragma unroll
        for(int nf = 0; nf < 4; nf++){
          uint2 pr;
          pr.x = pk2n((acc[mf][nf][0]+b0)*sc, (acc[mf][nf][1]+b1)*sc);
          pr.y = pk2n((acc[mf][nf][2]+b2)*sc, (acc[mf][nf][3]+b3)*sc);
          *reinterpret_cast<uint2*>(&scr[(16*nf + ln)*40 + 16*mf2 + 4*g]) = pr;
        }
      }
      asm volatile("s_waitcnt lgkmcnt(0)" ::: "memory");
      __builtin_amdgcn_sched_barrier(0);
      const unsigned short* rp = &scr[l*40];
      uint4 r0 = *reinterpret_cast<const uint4*>(rp);
      uint4 r1 = *reinterpret_cast<const uint4*>(rp+8);
      uint4 r2 = *reinterpret_cast<const uint4*>(rp+16);
      uint4 r3 = *reinterpret_cast<const uint4*>(rp+24);
      unsigned short* dp = T + ((size_t)(b*1024 + nbase + l))*1024 + obase + 32*h2;
      *reinterpret_cast<uint4*>(dp)    = r0;
      *reinterpret_cast<uint4*>(dp+8)  = r1;
      *reinterpret_cast<uint4*>(dp+16) = r2;
      *reinterpret_cast<uint4*>(dp+24) = r3;
    }
  } else {
    #pragma unroll
    for(int h2 = 0; h2 < 2; h2++){
      asm volatile("s_waitcnt lgkmcnt(0)" ::: "memory");
      __builtin_amdgcn_sched_barrier(0);
      #pragma unroll
      for(int nf2 = 0; nf2 < 2; nf2++){
        int nf = 2*h2 + nf2;
        #pragma unroll
        for(int mf = 0; mf < 4; mf++){
          int og = obase + 16*mf + 4*g;
          #pragma unroll
          for(int r = 0; r < 4; r++)
            scr[(16*mf + 4*g + r)*40 + 16*nf2 + ln] = bfn(acc[mf][nf][r] + bias[og+r]);
        }
      }
      asm volatile("s_waitcnt lgkmcnt(0)" ::: "memory");
      __builtin_amdgcn_sched_barrier(0);
      const unsigned short* rp = &scr[l*40];
      uint4 r0 = *reinterpret_cast<const uint4*>(rp);
      uint4 r1 = *reinterpret_cast<const uint4*>(rp+8);
      uint4 r2 = *reinterpret_cast<const uint4*>(rp+16);
      uint4 r3 = *reinterpret_cast<const uint4*>(rp+24);
      unsigned short* dp = V + ((size_t)(b*512 + obase - 1024 + l))*1024 + nbase + 32*h2;
      *reinterpret_cast<uint4*>(dp)    = r0;
      *reinterpret_cast<uint4*>(dp+8)  = r1;
      *reinterpret_cast<uint4*>(dp+16) = r2;
      *reinterpret_cast<uint4*>(dp+24) = r3;
    }
  }
}

// ---------------- Flash attention: K global->register (no KT tile; LDS 24 KB ->
// 6 blocks/CU), V gload_lds dbuf + XOR swizzle, counted vmcnt(8) + raw s_barrier
// so K prefetches stay in flight across the barrier, no-max exp2 softmax ----------------
__global__ __launch_bounds__(256) void attn_bf_k(const unsigned short* __restrict__ T,
                                                 const unsigned short* __restrict__ V,
                                                 unsigned short* __restrict__ attT){
  __shared__ __align__(16) unsigned short Vt[2][64*64];
  __shared__ __align__(16) unsigned int   Pl[4*16*32];   // pitch 32 + XOR swizzle
  int tid = threadIdx.x;
  // XCD swizzle: all 16 n0-blocks of a head share id%8 (same XCD) -> K/V L2-resident
  int id = blockIdx.x;
  int bh = (id >> 7) * 8 + (id & 7);
  int n0 = ((id >> 3) & 15) * 64;
  int b = bh >> 3, h = bh & 7;
  int wq = tid >> 6, ln = tid & 15, g = (tid >> 4) & 3;
  int l = tid & 63;
  int nl = n0 + wq*16 + ln;                 // this lane's q-row
  const unsigned short* Tb = T + ((size_t)b << 20);
  bf16x8 qf0 = *reinterpret_cast<const bf16x8*>(Tb + (size_t)nl*1024 + h*64 + 8*g);
  bf16x8 qf1 = *reinterpret_cast<const bf16x8*>(Tb + (size_t)nl*1024 + h*64 + 32 + 8*g);
  f32x4 acc[4] = {};
  float l_part = 0.f;
  const unsigned short* kg = Tb + 512 + h*64;
  const unsigned short* vg = V + ((size_t)(b*512 + h*64))*1024;
  int pbase = wq*512 + ln*32;
  int psw = (ln & 7) << 2;                  // Pl word swizzle
  int swz  = (((l & 7) << 3) ^ ((l >> 3) << 3));
  const unsigned short* vsrc = vg + (size_t)(wq*16 + (l>>3))*1024 + swz;
  int rsw = (ln & 7) << 3;
  int ro0 = (8*g) ^ rsw, ro1 = (32 + 8*g) ^ rsw;
  // prologue: stage V tile 0; load K tile 0 fragments into registers
  {
    unsigned short* vb = &Vt[0][wq*16*64];
    gl_lds16(vsrc,            vb);
    gl_lds16(vsrc + 8*1024,   vb + 8*64);
  }
  bf16x8 ka0[4], ka1[4];
  #pragma unroll
  for(int mf = 0; mf < 4; mf++){
    const unsigned short* kr = kg + (size_t)(16*mf + ln)*1024 + 8*g;
    ka0[mf] = *reinterpret_cast<const bf16x8*>(kr);
    ka1[mf] = *reinterpret_cast<const bf16x8*>(kr + 32);
  }
  __syncthreads();
  for(int t = 0; t < 16; t++){
    int buf = t & 1;
    if(t < 15){          // stage next V tile (oldest vm ops this iteration)
      int m1 = (t + 1) * 64;
      unsigned short* vb = &Vt[buf^1][wq*16*64];
      gl_lds16(vsrc + m1,            vb);
      gl_lds16(vsrc + 8*1024 + m1,   vb + 8*64);
    }
    // QK^T: register-only MFMA (K fragments prefetched a full tile ago)
    f32x4 sf[4];
    #pragma unroll
    for(int mf = 0; mf < 4; mf++){
      f32x4 z = {0.f, 0.f, 0.f, 0.f};
      z = MFMA16(ka0[mf], qf0, z);
      sf[mf] = MFMA16(ka1[mf], qf1, z);
    }
    // issue next K fragment loads (latency hidden by softmax+PV+barrier distance)
    if(t < 15){
      int m1 = (t + 1) * 64;
      #pragma unroll
      for(int mf = 0; mf < 4; mf++){
        const unsigned short* kr = kg + (size_t)(m1 + 16*mf + ln)*1024 + 8*g;
        ka0[mf] = *reinterpret_cast<const bf16x8*>(kr);
        ka1[mf] = *reinterpret_cast<const bf16x8*>(kr + 32);
      }
    }
    // p = exp2(s); per-lane l partial (no max tracking: scale cancels in the ratio)
    float p[16];
    #pragma unroll
    for(int mf = 0; mf < 4; mf++)
      #pragma unroll
      for(int r = 0; r < 4; r++){
        float v = EXP2(sf[mf][r]);
        p[mf*4 + r] = v;
        l_part += v;
      }
    // pack P (bf16 pairs) into per-wave LDS (XOR-swizzled), re-read as B-frags
    #pragma unroll
    for(int mt = 0; mt < 4; mt++){
      Pl[pbase + ((8*mt + 2*g + 0) ^ psw)] = pk2n(p[4*mt + 0], p[4*mt + 1]);
      Pl[pbase + ((8*mt + 2*g + 1) ^ psw)] = pk2n(p[4*mt + 2], p[4*mt + 3]);
    }
    asm volatile("s_waitcnt lgkmcnt(0)" ::: "memory");   // wave-local Pl ordering
    __builtin_amdgcn_sched_barrier(0);
    union { uint4 u; bf16x8 hv; } pb0, pb1;
    pb0.u = *reinterpret_cast<const uint4*>(&Pl[pbase + ((4*g) ^ psw)]);
    pb1.u = *reinterpret_cast<const uint4*>(&Pl[pbase + ((16 + 4*g) ^ psw)]);
    // PV from swizzled Vt[buf]
    #pragma unroll
    for(int cf = 0; cf < 4; cf++){
      bf16x8 v0 = *reinterpret_cast<const bf16x8*>(&Vt[buf][(16*cf + ln)*64 + ro0]);
      bf16x8 v1 = *reinterpret_cast<const bf16x8*>(&Vt[buf][(16*cf + ln)*64 + ro1]);
      acc[cf] = MFMA16(v0, pb0.hv, acc[cf]);
      acc[cf] = MFMA16(v1, pb1.hv, acc[cf]);
    }
    // counted-vmcnt barrier: V(t+1)'s 2 gl_lds (oldest) must land; K(t+1)'s
    // 8 register loads may stay in flight across the barrier (r7's fix)
    if(t < 15){
      __builtin_amdgcn_sched_barrier(0);
      asm volatile("s_waitcnt vmcnt(8)" ::: "memory");
      __builtin_amdgcn_sched_barrier(0);
      __builtin_amdgcn_s_barrier();
    }
  }
  float lsum = l_part;
  lsum += __shfl_xor(lsum, 16);
  lsum += __shfl_xor(lsum, 32);
  float inv = 1.f / lsum;
  unsigned short* op = attT + ((size_t)(b*1024 + nl))*512 + h*64;
  #pragma unroll
  for(int cf = 0; cf < 4; cf++){
    uint2 pr;
    pr.x = pk2n(acc[cf][0]*inv, acc[cf][1]*inv);
    pr.y = pk2n(acc[cf][2]*inv, acc[cf][3]*inv);
    *reinterpret_cast<uint2*>(op + 16*cf + 4*g) = pr;
  }
}

// ---------------- proj GEMM (bf16 A and B, BK=64 dbuf counted-vmcnt) + bias + residual ----------------
__global__ __launch_bounds__(256) void proj_mm(const unsigned short* __restrict__ A,
                                               const unsigned short* __restrict__ Bx,
                                               const float* __restrict__ bias,
                                               const float* __restrict__ resid,
                                               float* __restrict__ out){
  __shared__ __align__(16) unsigned short As[2][128*64], Bs[2][128*64];
  int tid = threadIdx.x;
  int n0 = blockIdx.x*128, o0 = blockIdx.y*128, b = blockIdx.z;
  int wid = tid >> 6, wr = wid >> 1, wc = wid & 1, ln = tid & 15, g = (tid >> 4) & 3;
  int l = tid & 63;
  int rsw = (ln & 7) << 3;
  int srow = 32*wid + (l >> 3);
  int scol = (((l & 7) ^ (l >> 3)) << 3);
  const unsigned short* Ag = A  + (size_t)(o0 + srow)*512 + scol;
  const unsigned short* Bg = Bx + ((size_t)(b*1024 + n0 + srow))*512 + scol;
  f32x4 acc[4][4] = {};
  #pragma unroll
  for(int c = 0; c < 4; c++){
    gl_lds16(Ag + (size_t)(8*c)*512, &As[0][(32*wid + 8*c)*64]);
    gl_lds16(Bg + (size_t)(8*c)*512, &Bs[0][(32*wid + 8*c)*64]);
  }
  for(int t = 0; t < 8; t++){
    int buf = t & 1;
    if(t < 7){
      int k1 = (t + 1) * 64;
      #pragma unroll
      for(int c = 0; c < 4; c++){
        gl_lds16(Ag + (size_t)(8*c)*512 + k1, &As[buf^1][(32*wid + 8*c)*64]);
        gl_lds16(Bg + (size_t)(8*c)*512 + k1, &Bs[buf^1][(32*wid + 8*c)*64]);
      }
      asm volatile("s_waitcnt vmcnt(8)" ::: "memory");
    } else {
      asm volatile("s_waitcnt vmcnt(0)" ::: "memory");
    }
    __builtin_amdgcn_sched_barrier(0);
    __builtin_amdgcn_s_barrier();
    __builtin_amdgcn_sched_barrier(0);
    #pragma unroll
    for(int kh = 0; kh < 2; kh++){
      int ro = (kh*32 + 8*g) ^ rsw;
      bf16x8 af[4], bfv[4];
      #pragma unroll
      for(int mf = 0; mf < 4; mf++)
        af[mf] = *reinterpret_cast<const bf16x8*>(&As[buf][(wr*64 + 16*mf + ln)*64 + ro]);
      #pragma unroll
      for(int nf = 0; nf < 4; nf++)
        bfv[nf] = *reinterpret_cast<const bf16x8*>(&Bs[buf][(wc*64 + 16*nf + ln)*64 + ro]);
      #pragma unroll
      for(int mf = 0; mf < 4; mf++)
        #pragma unroll
        for(int nf = 0; nf < 4; nf++)
          acc[mf][nf] = MFMA16(af[mf], bfv[nf], acc[mf][nf]);
    }
    __builtin_amdgcn_sched_barrier(0);
    __builtin_amdgcn_s_barrier();
  }
  #pragma unroll
  for(int mf = 0; mf < 4; mf++)
    #pragma unroll
    for(int r = 0; r < 4; r++){
      int o = o0 + wr*64 + 16*mf + 4*g + r;
      float bo = bias[o];
      #pragma unroll
      for(int nf = 0; nf < 4; nf++){
        int n = n0 + wc*64 + 16*nf + ln;
        size_t off = ((size_t)(b*512 + o))*1024 + n;
        out[off] = acc[mf][nf][r] + bo + resid[off];
      }
    }
}

extern "C" void kernel_launch(void* const* d_in, const int* in_sizes, int n_in,
                              void* d_out, int out_size, void* d_ws, size_t ws_size,
                              hipStream_t stream){
  const float* x     = (const float*)d_in[0];
  const float* gnw   = (const float*)d_in[1];
  const float* gnb   = (const float*)d_in[2];
  const float* qkvw  = (const float*)d_in[3];
  const float* qkvb  = (const float*)d_in[4];
  const float* projw = (const float*)d_in[5];
  const float* projb = (const float*)d_in[6];
  float* out = (float*)d_out;

  char* w = (char*)d_ws;
  unsigned short* wqb = (unsigned short*)w;  w += (size_t)1536*512*2;
  unsigned short* wpb = (unsigned short*)w;  w += (size_t)512*512*2;
  unsigned short* xnT = (unsigned short*)w;  w += (size_t)16*1024*512*2;
  unsigned short* Tqk = (unsigned short*)w;  w += (size_t)16*1024*1024*2;
  unsigned short* Vb  = (unsigned short*)w;  w += (size_t)16*512*1024*2;
  unsigned short* attT = (unsigned short*)w; w += (size_t)16*1024*512*2;

  hipLaunchKernelGGL(pre_k, dim3(384), dim3(512), 0, stream,
                     x, gnw, gnb, xnT, qkvw, projw,
                     (unsigned int*)wqb, (unsigned int*)wpb);
  hipLaunchKernelGGL(qkv_mm, dim3(8, 12, 16), dim3(256), 0, stream, wqb, xnT, qkvb, Tqk, Vb);
  hipLaunchKernelGGL(attn_bf_k, dim3(2048), dim3(256), 0, stream, Tqk, Vb, attT);
  hipLaunchKernelGGL(proj_mm, dim3(8, 4, 16), dim3(256), 0, stream, wpb, attT, projb, x, out);
}

// Round 17
// 149.168 us; speedup vs baseline: 1.4413x; 1.4413x over previous
//
#include <hip/hip_runtime.h>
#include <hip/hip_bf16.h>
#include <math.h>

typedef short bf16x8 __attribute__((ext_vector_type(8)));
typedef float f32x4  __attribute__((ext_vector_type(4)));
#define MFMA16(a,b,c) __builtin_amdgcn_mfma_f32_16x16x32_bf16(a,b,c,0,0,0)

#define EPSF 1e-5f
#define QSC 0.18033688f   // 0.125 * log2(e), folded into Q

#if __has_builtin(__builtin_amdgcn_exp2f)
#define EXP2(x) __builtin_amdgcn_exp2f(x)
#else
#define EXP2(x) exp2f(x)
#endif

__device__ __forceinline__ unsigned int pk2n(float a, float b){
  __hip_bfloat162 h = __float22bfloat162_rn(make_float2(a, b));
  return *reinterpret_cast<unsigned int*>(&h);
}
__device__ __forceinline__ unsigned short bfn(float f){
  __hip_bfloat16 h = __float2bfloat16(f);
  return *reinterpret_cast<unsigned short*>(&h);
}
__device__ __forceinline__ float4 ld4(const float* p){ return *reinterpret_cast<const float4*>(p); }

// async global->LDS, 16B per lane; LDS dest = wave-uniform base + lane*16
__device__ __forceinline__ void gl_lds16(const unsigned short* g, unsigned short* l){
  __builtin_amdgcn_global_load_lds(
      (const __attribute__((address_space(1))) unsigned int*)g,
      (__attribute__((address_space(3))) unsigned int*)l, 16, 0, 0);
}

// ---------------- preamble: fused GroupNorm (blocks 0..127) + weight cvt (blocks 128..383) ----------------
__global__ __launch_bounds__(512) void pre_k(const float* __restrict__ x,
                                             const float* __restrict__ gnw,
                                             const float* __restrict__ gnb,
                                             unsigned short* __restrict__ xnT,
                                             const float* __restrict__ qkvw,
                                             const float* __restrict__ projw,
                                             unsigned int* __restrict__ wqb,
                                             unsigned int* __restrict__ wpb){
  __shared__ float Xl[2][64*65];
  __shared__ float red[16];
  int blk = blockIdx.x;
  int tid = threadIdx.x;
  if(blk >= 128){
    const float* src; unsigned int* dst; int base;
    if(blk < 320){ src = qkvw; dst = wqb; base = 128; }
    else         { src = projw; dst = wpb; base = 320; }
    int i = (blk - base)*1024 + tid*2;
    #pragma unroll
    for(int j = 0; j < 2; j++){
      float4 v = reinterpret_cast<const float4*>(src)[i + j];
      uint2 r; r.x = pk2n(v.x, v.y); r.y = pk2n(v.z, v.w);
      reinterpret_cast<uint2*>(dst)[i + j] = r;
    }
    return;
  }
  int b = blk >> 3, g = blk & 7;
  const float4* p4 = reinterpret_cast<const float4*>(x + (size_t)blk * 65536);
  float s1 = 0.f, s2 = 0.f;
  for(int i = tid; i < 16384; i += 512){
    float4 v = p4[i];
    s1 += (v.x + v.y) + (v.z + v.w);
    s2 += v.x*v.x + v.y*v.y + v.z*v.z + v.w*v.w;
  }
  #pragma unroll
  for(int off = 32; off; off >>= 1){ s1 += __shfl_xor(s1, off); s2 += __shfl_xor(s2, off); }
  if((tid & 63) == 0){ red[tid >> 6] = s1; red[8 + (tid >> 6)] = s2; }
  __syncthreads();
  float a = 0.f, b2 = 0.f;
  #pragma unroll
  for(int w = 0; w < 8; w++){ a += red[w]; b2 += red[8 + w]; }
  float mean = a * (1.f / 65536.f);
  float rstd = rsqrtf(b2 * (1.f / 65536.f) - mean * mean + EPSF);
  int half = tid >> 8, t256 = tid & 255;
  int nq = t256 & 15, rr = t256 >> 4;
  int c0 = g * 64;
  for(int it = 0; it < 8; it++){
    int n0 = (it*2 + half) * 64;
    __syncthreads();
    #pragma unroll
    for(int p = 0; p < 4; p++){
      int cl = p * 16 + rr, c = c0 + cl;
      float s = rstd * gnw[c], t = gnb[c] - mean * s;
      float4 v = ld4(x + ((size_t)(b*512 + c))*1024 + n0 + 4*nq);
      Xl[half][(4*nq+0)*65 + cl] = v.x*s + t;
      Xl[half][(4*nq+1)*65 + cl] = v.y*s + t;
      Xl[half][(4*nq+2)*65 + cl] = v.z*s + t;
      Xl[half][(4*nq+3)*65 + cl] = v.w*s + t;
    }
    __syncthreads();
    int n = t256 >> 2, cq = t256 & 3;
    float f[16];
    #pragma unroll
    for(int k = 0; k < 16; k++) f[k] = Xl[half][n*65 + 16*cq + k];
    uint4 w0, w1;
    w0.x = pk2n(f[0],f[1]);  w0.y = pk2n(f[2],f[3]);  w0.z = pk2n(f[4],f[5]);  w0.w = pk2n(f[6],f[7]);
    w1.x = pk2n(f[8],f[9]);  w1.y = pk2n(f[10],f[11]);w1.z = pk2n(f[12],f[13]);w1.w = pk2n(f[14],f[15]);
    unsigned short* dp = xnT + ((size_t)(b*1024 + n0 + n))*512 + c0 + 16*cq;
    *reinterpret_cast<uint4*>(dp)     = w0;
    *reinterpret_cast<uint4*>(dp + 8) = w1;
  }
}

// ---- GEMM core: BK=64 DOUBLE-buffered, counted vmcnt(8) + raw s_barrier (T4),
// gl_lds staging, XOR-swizzled linear LDS (r15 measured-best). ----

// ---------------- QKV GEMM: Q,K transposed (Q pre-scaled) + V natural ----------------
__global__ __launch_bounds__(256) void qkv_mm(const unsigned short* __restrict__ A,
                                              const unsigned short* __restrict__ Bx,
                                              const float* __restrict__ bias,
                                              unsigned short* __restrict__ T,
                                              unsigned short* __restrict__ V){
  __shared__ __align__(16) unsigned short As[2][128*64], Bs[2][128*64];
  int tid = threadIdx.x;
  int n0 = blockIdx.x*128, o0 = blockIdx.y*128, b = blockIdx.z;
  int wid = tid >> 6, wr = wid >> 1, wc = wid & 1, ln = tid & 15, g = (tid >> 4) & 3;
  int l = tid & 63;
  int rsw = (ln & 7) << 3;
  int srow = 32*wid + (l >> 3);
  int scol = (((l & 7) ^ (l >> 3)) << 3);
  const unsigned short* Ag = A  + (size_t)(o0 + srow)*512 + scol;
  const unsigned short* Bg = Bx + ((size_t)(b*1024 + n0 + srow))*512 + scol;
  f32x4 acc[4][4] = {};
  #pragma unroll
  for(int c = 0; c < 4; c++){
    gl_lds16(Ag + (size_t)(8*c)*512, &As[0][(32*wid + 8*c)*64]);
    gl_lds16(Bg + (size_t)(8*c)*512, &Bs[0][(32*wid + 8*c)*64]);
  }
  for(int t = 0; t < 8; t++){
    int buf = t & 1;
    if(t < 7){
      int k1 = (t + 1) * 64;
      #pragma unroll
      for(int c = 0; c < 4; c++){
        gl_lds16(Ag + (size_t)(8*c)*512 + k1, &As[buf^1][(32*wid + 8*c)*64]);
        gl_lds16(Bg + (size_t)(8*c)*512 + k1, &Bs[buf^1][(32*wid + 8*c)*64]);
      }
      asm volatile("s_waitcnt vmcnt(8)" ::: "memory");   // tile t's 8 loads done
    } else {
      asm volatile("s_waitcnt vmcnt(0)" ::: "memory");
    }
    __builtin_amdgcn_sched_barrier(0);
    __builtin_amdgcn_s_barrier();
    __builtin_amdgcn_sched_barrier(0);
    #pragma unroll
    for(int kh = 0; kh < 2; kh++){
      int ro = (kh*32 + 8*g) ^ rsw;
      bf16x8 af[4], bfv[4];
      #pragma unroll
      for(int mf = 0; mf < 4; mf++)
        af[mf] = *reinterpret_cast<const bf16x8*>(&As[buf][(wr*64 + 16*mf + ln)*64 + ro]);
      #pragma unroll
      for(int nf = 0; nf < 4; nf++)
        bfv[nf] = *reinterpret_cast<const bf16x8*>(&Bs[buf][(wc*64 + 16*nf + ln)*64 + ro]);
      #pragma unroll
      for(int mf = 0; mf < 4; mf++)
        #pragma unroll
        for(int nf = 0; nf < 4; nf++)
          acc[mf][nf] = MFMA16(af[mf], bfv[nf], acc[mf][nf]);
    }
    __builtin_amdgcn_sched_barrier(0);
    __builtin_amdgcn_s_barrier();
  }
  int obase = o0 + wr*64, nbase = n0 + wc*64;
  unsigned short* scr = &As[0][0] + wid * 2560;          // 64 rows x 40 pitch, per-wave scratch
  float sc = (obase < 512) ? QSC : 1.0f;
  if(obase < 1024){
    #pragma unroll
    for(int h2 = 0; h2 < 2; h2++){
      asm volatile("s_waitcnt lgkmcnt(0)" ::: "memory");
      __builtin_amdgcn_sched_barrier(0);
      #pragma unroll
      for(int mf2 = 0; mf2 < 2; mf2++){
        int mf = 2*h2 + mf2;
        int og = obase + 16*mf + 4*g;
        float b0 = bias[og], b1 = bias[og+1], b2 = bias[og+2], b3 = bias[og+3];
        #pragma unroll
        for(int nf = 0; nf < 4; nf++){
          uint2 pr;
          pr.x = pk2n((acc[mf][nf][0]+b0)*sc, (acc[mf][nf][1]+b1)*sc);
          pr.y = pk2n((acc[mf][nf][2]+b2)*sc, (acc[mf][nf][3]+b3)*sc);
          *reinterpret_cast<uint2*>(&scr[(16*nf + ln)*40 + 16*mf2 + 4*g]) = pr;
        }
      }
      asm volatile("s_waitcnt lgkmcnt(0)" ::: "memory");
      __builtin_amdgcn_sched_barrier(0);
      const unsigned short* rp = &scr[l*40];
      uint4 r0 = *reinterpret_cast<const uint4*>(rp);
      uint4 r1 = *reinterpret_cast<const uint4*>(rp+8);
      uint4 r2 = *reinterpret_cast<const uint4*>(rp+16);
      uint4 r3 = *reinterpret_cast<const uint4*>(rp+24);
      unsigned short* dp = T + ((size_t)(b*1024 + nbase + l))*1024 + obase + 32*h2;
      *reinterpret_cast<uint4*>(dp)    = r0;
      *reinterpret_cast<uint4*>(dp+8)  = r1;
      *reinterpret_cast<uint4*>(dp+16) = r2;
      *reinterpret_cast<uint4*>(dp+24) = r3;
    }
  } else {
    #pragma unroll
    for(int h2 = 0; h2 < 2; h2++){
      asm volatile("s_waitcnt lgkmcnt(0)" ::: "memory");
      __builtin_amdgcn_sched_barrier(0);
      #pragma unroll
      for(int nf2 = 0; nf2 < 2; nf2++){
        int nf = 2*h2 + nf2;
        #pragma unroll
        for(int mf = 0; mf < 4; mf++){
          int og = obase + 16*mf + 4*g;
          #pragma unroll
          for(int r = 0; r < 4; r++)
            scr[(16*mf + 4*g + r)*40 + 16*nf2 + ln] = bfn(acc[mf][nf][r] + bias[og+r]);
        }
      }
      asm volatile("s_waitcnt lgkmcnt(0)" ::: "memory");
      __builtin_amdgcn_sched_barrier(0);
      const unsigned short* rp = &scr[l*40];
      uint4 r0 = *reinterpret_cast<const uint4*>(rp);
      uint4 r1 = *reinterpret_cast<const uint4*>(rp+8);
      uint4 r2 = *reinterpret_cast<const uint4*>(rp+16);
      uint4 r3 = *reinterpret_cast<const uint4*>(rp+24);
      unsigned short* dp = V + ((size_t)(b*512 + obase - 1024 + l))*1024 + nbase + 32*h2;
      *reinterpret_cast<uint4*>(dp)    = r0;
      *reinterpret_cast<uint4*>(dp+8)  = r1;
      *reinterpret_cast<uint4*>(dp+16) = r2;
      *reinterpret_cast<uint4*>(dp+24) = r3;
    }
  }
}

// ---------------- Flash attention (r15 measured-best + setprio): gload_lds staging,
// XOR-swizzled LDS, dbuf K+V, 1 barrier/tile, no-max exp2 softmax, Pl repack ----
__global__ __launch_bounds__(256) void attn_bf_k(const unsigned short* __restrict__ T,
                                                 const unsigned short* __restrict__ V,
                                                 unsigned short* __restrict__ attT){
  __shared__ __align__(16) unsigned short KT[2][64*64];
  __shared__ __align__(16) unsigned short Vt[2][64*64];
  __shared__ __align__(16) unsigned int   Pl[4*16*32];   // pitch 32 + XOR swizzle
  int tid = threadIdx.x;
  int id = blockIdx.x;
  int bh = (id >> 7) * 8 + (id & 7);
  int n0 = ((id >> 3) & 15) * 64;
  int b = bh >> 3, h = bh & 7;
  int wq = tid >> 6, ln = tid & 15, g = (tid >> 4) & 3;
  int l = tid & 63;
  int nl = n0 + wq*16 + ln;
  const unsigned short* Tb = T + ((size_t)b << 20);
  bf16x8 qf0 = *reinterpret_cast<const bf16x8*>(Tb + (size_t)nl*1024 + h*64 + 8*g);
  bf16x8 qf1 = *reinterpret_cast<const bf16x8*>(Tb + (size_t)nl*1024 + h*64 + 32 + 8*g);
  f32x4 acc[4] = {};
  float l_part = 0.f;
  const unsigned short* kg = Tb + 512 + h*64;
  const unsigned short* vg = V + ((size_t)(b*512 + h*64))*1024;
  int pbase = wq*512 + ln*32;
  int psw = (ln & 7) << 2;
  int swz  = (((l & 7) << 3) ^ ((l >> 3) << 3));
  const unsigned short* ksrc = kg + (size_t)(wq*16 + (l>>3))*1024 + swz;
  const unsigned short* vsrc = vg + (size_t)(wq*16 + (l>>3))*1024 + swz;
  int rsw = (ln & 7) << 3;
  int ro0 = (8*g) ^ rsw, ro1 = (32 + 8*g) ^ rsw;
  {
    unsigned short* kb = &KT[0][wq*16*64];
    unsigned short* vb = &Vt[0][wq*16*64];
    gl_lds16(ksrc,            kb);
    gl_lds16(ksrc + 8*1024,   kb + 8*64);
    gl_lds16(vsrc,            vb);
    gl_lds16(vsrc + 8*1024,   vb + 8*64);
  }
  __syncthreads();
  for(int t = 0; t < 16; t++){
    int buf = t & 1;
    if(t < 15){
      int m1 = (t + 1) * 64;
      unsigned short* kb = &KT[buf^1][wq*16*64];
      unsigned short* vb = &Vt[buf^1][wq*16*64];
      gl_lds16(ksrc + (size_t)m1*1024,          kb);
      gl_lds16(ksrc + (size_t)(m1+8)*1024,      kb + 8*64);
      gl_lds16(vsrc + m1,                       vb);
      gl_lds16(vsrc + 8*1024 + m1,              vb + 8*64);
    }
    f32x4 sf[4];
    __builtin_amdgcn_s_setprio(1);
    #pragma unroll
    for(int mf = 0; mf < 4; mf++){
      bf16x8 a0 = *reinterpret_cast<const bf16x8*>(&KT[buf][(16*mf + ln)*64 + ro0]);
      bf16x8 a1 = *reinterpret_cast<const bf16x8*>(&KT[buf][(16*mf + ln)*64 + ro1]);
      f32x4 z = {0.f, 0.f, 0.f, 0.f};
      z = MFMA16(a0, qf0, z);
      sf[mf] = MFMA16(a1, qf1, z);
    }
    __builtin_amdgcn_s_setprio(0);
    float p[16];
    #pragma unroll
    for(int mf = 0; mf < 4; mf++)
      #pragma unroll
      for(int r = 0; r < 4; r++){
        float v = EXP2(sf[mf][r]);
        p[mf*4 + r] = v;
        l_part += v;
      }
    #pragma unroll
    for(int mt = 0; mt < 4; mt++){
      Pl[pbase + ((8*mt + 2*g + 0) ^ psw)] = pk2n(p[4*mt + 0], p[4*mt + 1]);
      Pl[pbase + ((8*mt + 2*g + 1) ^ psw)] = pk2n(p[4*mt + 2], p[4*mt + 3]);
    }
    asm volatile("s_waitcnt lgkmcnt(0)" ::: "memory");
    __builtin_amdgcn_sched_barrier(0);
    union { uint4 u; bf16x8 hv; } pb0, pb1;
    pb0.u = *reinterpret_cast<const uint4*>(&Pl[pbase + ((4*g) ^ psw)]);
    pb1.u = *reinterpret_cast<const uint4*>(&Pl[pbase + ((16 + 4*g) ^ psw)]);
    __builtin_amdgcn_s_setprio(1);
    #pragma unroll
    for(int cf = 0; cf < 4; cf++){
      bf16x8 v0 = *reinterpret_cast<const bf16x8*>(&Vt[buf][(16*cf + ln)*64 + ro0]);
      bf16x8 v1 = *reinterpret_cast<const bf16x8*>(&Vt[buf][(16*cf + ln)*64 + ro1]);
      acc[cf] = MFMA16(v0, pb0.hv, acc[cf]);
      acc[cf] = MFMA16(v1, pb1.hv, acc[cf]);
    }
    __builtin_amdgcn_s_setprio(0);
    __syncthreads();
  }
  float lsum = l_part;
  lsum += __shfl_xor(lsum, 16);
  lsum += __shfl_xor(lsum, 32);
  float inv = 1.f / lsum;
  unsigned short* op = attT + ((size_t)(b*1024 + nl))*512 + h*64;
  #pragma unroll
  for(int cf = 0; cf < 4; cf++){
    uint2 pr;
    pr.x = pk2n(acc[cf][0]*inv, acc[cf][1]*inv);
    pr.y = pk2n(acc[cf][2]*inv, acc[cf][3]*inv);
    *reinterpret_cast<uint2*>(op + 16*cf + 4*g) = pr;
  }
}

// ---------------- proj GEMM (bf16 A and B, BK=64 dbuf counted-vmcnt) + bias + residual ----------------
__global__ __launch_bounds__(256) void proj_mm(const unsigned short* __restrict__ A,
                                               const unsigned short* __restrict__ Bx,
                                               const float* __restrict__ bias,
                                               const float* __restrict__ resid,
                                               float* __restrict__ out){
  __shared__ __align__(16) unsigned short As[2][128*64], Bs[2][128*64];
  int tid = threadIdx.x;
  int n0 = blockIdx.x*128, o0 = blockIdx.y*128, b = blockIdx.z;
  int wid = tid >> 6, wr = wid >> 1, wc = wid & 1, ln = tid & 15, g = (tid >> 4) & 3;
  int l = tid & 63;
  int rsw = (ln & 7) << 3;
  int srow = 32*wid + (l >> 3);
  int scol = (((l & 7) ^ (l >> 3)) << 3);
  const unsigned short* Ag = A  + (size_t)(o0 + srow)*512 + scol;
  const unsigned short* Bg = Bx + ((size_t)(b*1024 + n0 + srow))*512 + scol;
  f32x4 acc[4][4] = {};
  #pragma unroll
  for(int c = 0; c < 4; c++){
    gl_lds16(Ag + (size_t)(8*c)*512, &As[0][(32*wid + 8*c)*64]);
    gl_lds16(Bg + (size_t)(8*c)*512, &Bs[0][(32*wid + 8*c)*64]);
  }
  for(int t = 0; t < 8; t++){
    int buf = t & 1;
    if(t < 7){
      int k1 = (t + 1) * 64;
      #pragma unroll
      for(int c = 0; c < 4; c++){
        gl_lds16(Ag + (size_t)(8*c)*512 + k1, &As[buf^1][(32*wid + 8*c)*64]);
        gl_lds16(Bg + (size_t)(8*c)*512 + k1, &Bs[buf^1][(32*wid + 8*c)*64]);
      }
      asm volatile("s_waitcnt vmcnt(8)" ::: "memory");
    } else {
      asm volatile("s_waitcnt vmcnt(0)" ::: "memory");
    }
    __builtin_amdgcn_sched_barrier(0);
    __builtin_amdgcn_s_barrier();
    __builtin_amdgcn_sched_barrier(0);
    #pragma unroll
    for(int kh = 0; kh < 2; kh++){
      int ro = (kh*32 + 8*g) ^ rsw;
      bf16x8 af[4], bfv[4];
      #pragma unroll
      for(int mf = 0; mf < 4; mf++)
        af[mf] = *reinterpret_cast<const bf16x8*>(&As[buf][(wr*64 + 16*mf + ln)*64 + ro]);
      #pragma unroll
      for(int nf = 0; nf < 4; nf++)
        bfv[nf] = *reinterpret_cast<const bf16x8*>(&Bs[buf][(wc*64 + 16*nf + ln)*64 + ro]);
      #pragma unroll
      for(int mf = 0; mf < 4; mf++)
        #pragma unroll
        for(int nf = 0; nf < 4; nf++)
          acc[mf][nf] = MFMA16(af[mf], bfv[nf], acc[mf][nf]);
    }
    __builtin_amdgcn_sched_barrier(0);
    __builtin_amdgcn_s_barrier();
  }
  #pragma unroll
  for(int mf = 0; mf < 4; mf++)
    #pragma unroll
    for(int r = 0; r < 4; r++){
      int o = o0 + wr*64 + 16*mf + 4*g + r;
      float bo = bias[o];
      #pragma unroll
      for(int nf = 0; nf < 4; nf++){
        int n = n0 + wc*64 + 16*nf + ln;
        size_t off = ((size_t)(b*512 + o))*1024 + n;
        out[off] = acc[mf][nf][r] + bo + resid[off];
      }
    }
}

extern "C" void kernel_launch(void* const* d_in, const int* in_sizes, int n_in,
                              void* d_out, int out_size, void* d_ws, size_t ws_size,
                              hipStream_t stream){
  const float* x     = (const float*)d_in[0];
  const float* gnw   = (const float*)d_in[1];
  const float* gnb   = (const float*)d_in[2];
  const float* qkvw  = (const float*)d_in[3];
  const float* qkvb  = (const float*)d_in[4];
  const float* projw = (const float*)d_in[5];
  const float* projb = (const float*)d_in[6];
  float* out = (float*)d_out;

  char* w = (char*)d_ws;
  unsigned short* wqb = (unsigned short*)w;  w += (size_t)1536*512*2;
  unsigned short* wpb = (unsigned short*)w;  w += (size_t)512*512*2;
  unsigned short* xnT = (unsigned short*)w;  w += (size_t)16*1024*512*2;
  unsigned short* Tqk = (unsigned short*)w;  w += (size_t)16*1024*1024*2;
  unsigned short* Vb  = (unsigned short*)w;  w += (size_t)16*512*1024*2;
  unsigned short* attT = (unsigned short*)w; w += (size_t)16*1024*512*2;

  hipLaunchKernelGGL(pre_k, dim3(384), dim3(512), 0, stream,
                     x, gnw, gnb, xnT, qkvw, projw,
                     (unsigned int*)wqb, (unsigned int*)wpb);
  hipLaunchKernelGGL(qkv_mm, dim3(8, 12, 16), dim3(256), 0, stream, wqb, xnT, qkvb, Tqk, Vb);
  hipLaunchKernelGGL(attn_bf_k, dim3(2048), dim3(256), 0, stream, Tqk, Vb, attT);
  hipLaunchKernelGGL(proj_mm, dim3(8, 4, 16), dim3(256), 0, stream, wpb, attT, projb, x, out);
}

// Round 18
// 147.783 us; speedup vs baseline: 1.4548x; 1.0094x over previous
//
#include <hip/hip_runtime.h>
#include <hip/hip_bf16.h>
#include <math.h>

typedef short bf16x8 __attribute__((ext_vector_type(8)));
typedef float f32x4  __attribute__((ext_vector_type(4)));
#define MFMA16(a,b,c) __builtin_amdgcn_mfma_f32_16x16x32_bf16(a,b,c,0,0,0)

#define EPSF 1e-5f
#define QSC 0.18033688f   // 0.125 * log2(e), folded into Q

#if __has_builtin(__builtin_amdgcn_exp2f)
#define EXP2(x) __builtin_amdgcn_exp2f(x)
#else
#define EXP2(x) exp2f(x)
#endif

__device__ __forceinline__ unsigned int pk2n(float a, float b){
  __hip_bfloat162 h = __float22bfloat162_rn(make_float2(a, b));
  return *reinterpret_cast<unsigned int*>(&h);
}
__device__ __forceinline__ unsigned short bfn(float f){
  __hip_bfloat16 h = __float2bfloat16(f);
  return *reinterpret_cast<unsigned short*>(&h);
}
__device__ __forceinline__ float4 ld4(const float* p){ return *reinterpret_cast<const float4*>(p); }

// async global->LDS, 16B per lane; LDS dest = wave-uniform base + lane*16
__device__ __forceinline__ void gl_lds16(const unsigned short* g, unsigned short* l){
  __builtin_amdgcn_global_load_lds(
      (const __attribute__((address_space(1))) unsigned int*)g,
      (__attribute__((address_space(3))) unsigned int*)l, 16, 0, 0);
}

// ---------------- preamble: fused GroupNorm (blocks 0..127) + weight cvt (blocks 128..383) ----------------
__global__ __launch_bounds__(512) void pre_k(const float* __restrict__ x,
                                             const float* __restrict__ gnw,
                                             const float* __restrict__ gnb,
                                             unsigned short* __restrict__ xnT,
                                             const float* __restrict__ qkvw,
                                             const float* __restrict__ projw,
                                             unsigned int* __restrict__ wqb,
                                             unsigned int* __restrict__ wpb){
  __shared__ float Xl[2][64*65];
  __shared__ float red[16];
  int blk = blockIdx.x;
  int tid = threadIdx.x;
  if(blk >= 128){
    const float* src; unsigned int* dst; int base;
    if(blk < 320){ src = qkvw; dst = wqb; base = 128; }
    else         { src = projw; dst = wpb; base = 320; }
    int i = (blk - base)*1024 + tid*2;
    #pragma unroll
    for(int j = 0; j < 2; j++){
      float4 v = reinterpret_cast<const float4*>(src)[i + j];
      uint2 r; r.x = pk2n(v.x, v.y); r.y = pk2n(v.z, v.w);
      reinterpret_cast<uint2*>(dst)[i + j] = r;
    }
    return;
  }
  int b = blk >> 3, g = blk & 7;
  const float4* p4 = reinterpret_cast<const float4*>(x + (size_t)blk * 65536);
  float s1 = 0.f, s2 = 0.f;
  for(int i = tid; i < 16384; i += 512){
    float4 v = p4[i];
    s1 += (v.x + v.y) + (v.z + v.w);
    s2 += v.x*v.x + v.y*v.y + v.z*v.z + v.w*v.w;
  }
  #pragma unroll
  for(int off = 32; off; off >>= 1){ s1 += __shfl_xor(s1, off); s2 += __shfl_xor(s2, off); }
  if((tid & 63) == 0){ red[tid >> 6] = s1; red[8 + (tid >> 6)] = s2; }
  __syncthreads();
  float a = 0.f, b2 = 0.f;
  #pragma unroll
  for(int w = 0; w < 8; w++){ a += red[w]; b2 += red[8 + w]; }
  float mean = a * (1.f / 65536.f);
  float rstd = rsqrtf(b2 * (1.f / 65536.f) - mean * mean + EPSF);
  int half = tid >> 8, t256 = tid & 255;
  int nq = t256 & 15, rr = t256 >> 4;
  int c0 = g * 64;
  for(int it = 0; it < 8; it++){
    int n0 = (it*2 + half) * 64;
    __syncthreads();
    #pragma unroll
    for(int p = 0; p < 4; p++){
      int cl = p * 16 + rr, c = c0 + cl;
      float s = rstd * gnw[c], t = gnb[c] - mean * s;
      float4 v = ld4(x + ((size_t)(b*512 + c))*1024 + n0 + 4*nq);
      Xl[half][(4*nq+0)*65 + cl] = v.x*s + t;
      Xl[half][(4*nq+1)*65 + cl] = v.y*s + t;
      Xl[half][(4*nq+2)*65 + cl] = v.z*s + t;
      Xl[half][(4*nq+3)*65 + cl] = v.w*s + t;
    }
    __syncthreads();
    int n = t256 >> 2, cq = t256 & 3;
    float f[16];
    #pragma unroll
    for(int k = 0; k < 16; k++) f[k] = Xl[half][n*65 + 16*cq + k];
    uint4 w0, w1;
    w0.x = pk2n(f[0],f[1]);  w0.y = pk2n(f[2],f[3]);  w0.z = pk2n(f[4],f[5]);  w0.w = pk2n(f[6],f[7]);
    w1.x = pk2n(f[8],f[9]);  w1.y = pk2n(f[10],f[11]);w1.z = pk2n(f[12],f[13]);w1.w = pk2n(f[14],f[15]);
    unsigned short* dp = xnT + ((size_t)(b*1024 + n0 + n))*512 + c0 + 16*cq;
    *reinterpret_cast<uint4*>(dp)     = w0;
    *reinterpret_cast<uint4*>(dp + 8) = w1;
  }
}

// ---- GEMM core: BK=64 DOUBLE-buffered, counted vmcnt(8) + raw s_barrier (T4),
// gl_lds staging, XOR-swizzled linear LDS (r15 measured-best). ----

// ---------------- QKV GEMM: Q,K transposed (Q pre-scaled) + V natural ----------------
__global__ __launch_bounds__(256) void qkv_mm(const unsigned short* __restrict__ A,
                                              const unsigned short* __restrict__ Bx,
                                              const float* __restrict__ bias,
                                              unsigned short* __restrict__ T,
                                              unsigned short* __restrict__ V){
  __shared__ __align__(16) unsigned short As[2][128*64], Bs[2][128*64];
  int tid = threadIdx.x;
  int n0 = blockIdx.x*128, o0 = blockIdx.y*128, b = blockIdx.z;
  int wid = tid >> 6, wr = wid >> 1, wc = wid & 1, ln = tid & 15, g = (tid >> 4) & 3;
  int l = tid & 63;
  int rsw = (ln & 7) << 3;
  int srow = 32*wid + (l >> 3);
  int scol = (((l & 7) ^ (l >> 3)) << 3);
  const unsigned short* Ag = A  + (size_t)(o0 + srow)*512 + scol;
  const unsigned short* Bg = Bx + ((size_t)(b*1024 + n0 + srow))*512 + scol;
  f32x4 acc[4][4] = {};
  #pragma unroll
  for(int c = 0; c < 4; c++){
    gl_lds16(Ag + (size_t)(8*c)*512, &As[0][(32*wid + 8*c)*64]);
    gl_lds16(Bg + (size_t)(8*c)*512, &Bs[0][(32*wid + 8*c)*64]);
  }
  for(int t = 0; t < 8; t++){
    int buf = t & 1;
    if(t < 7){
      int k1 = (t + 1) * 64;
      #pragma unroll
      for(int c = 0; c < 4; c++){
        gl_lds16(Ag + (size_t)(8*c)*512 + k1, &As[buf^1][(32*wid + 8*c)*64]);
        gl_lds16(Bg + (size_t)(8*c)*512 + k1, &Bs[buf^1][(32*wid + 8*c)*64]);
      }
      asm volatile("s_waitcnt vmcnt(8)" ::: "memory");   // tile t's 8 loads done
    } else {
      asm volatile("s_waitcnt vmcnt(0)" ::: "memory");
    }
    __builtin_amdgcn_sched_barrier(0);
    __builtin_amdgcn_s_barrier();
    __builtin_amdgcn_sched_barrier(0);
    #pragma unroll
    for(int kh = 0; kh < 2; kh++){
      int ro = (kh*32 + 8*g) ^ rsw;
      bf16x8 af[4], bfv[4];
      #pragma unroll
      for(int mf = 0; mf < 4; mf++)
        af[mf] = *reinterpret_cast<const bf16x8*>(&As[buf][(wr*64 + 16*mf + ln)*64 + ro]);
      #pragma unroll
      for(int nf = 0; nf < 4; nf++)
        bfv[nf] = *reinterpret_cast<const bf16x8*>(&Bs[buf][(wc*64 + 16*nf + ln)*64 + ro]);
      #pragma unroll
      for(int mf = 0; mf < 4; mf++)
        #pragma unroll
        for(int nf = 0; nf < 4; nf++)
          acc[mf][nf] = MFMA16(af[mf], bfv[nf], acc[mf][nf]);
    }
    __builtin_amdgcn_sched_barrier(0);
    __builtin_amdgcn_s_barrier();
  }
  int obase = o0 + wr*64, nbase = n0 + wc*64;
  unsigned short* scr = &As[0][0] + wid * 2560;          // 64 rows x 40 pitch, per-wave scratch
  float sc = (obase < 512) ? QSC : 1.0f;
  if(obase < 1024){
    #pragma unroll
    for(int h2 = 0; h2 < 2; h2++){
      asm volatile("s_waitcnt lgkmcnt(0)" ::: "memory");
      __builtin_amdgcn_sched_barrier(0);
      #pragma unroll
      for(int mf2 = 0; mf2 < 2; mf2++){
        int mf = 2*h2 + mf2;
        int og = obase + 16*mf + 4*g;
        float b0 = bias[og], b1 = bias[og+1], b2 = bias[og+2], b3 = bias[og+3];
        #pragma unroll
        for(int nf = 0; nf < 4; nf++){
          uint2 pr;
          pr.x = pk2n((acc[mf][nf][0]+b0)*sc, (acc[mf][nf][1]+b1)*sc);
          pr.y = pk2n((acc[mf][nf][2]+b2)*sc, (acc[mf][nf][3]+b3)*sc);
          *reinterpret_cast<uint2*>(&scr[(16*nf + ln)*40 + 16*mf2 + 4*g]) = pr;
        }
      }
      asm volatile("s_waitcnt lgkmcnt(0)" ::: "memory");
      __builtin_amdgcn_sched_barrier(0);
      const unsigned short* rp = &scr[l*40];
      uint4 r0 = *reinterpret_cast<const uint4*>(rp);
      uint4 r1 = *reinterpret_cast<const uint4*>(rp+8);
      uint4 r2 = *reinterpret_cast<const uint4*>(rp+16);
      uint4 r3 = *reinterpret_cast<const uint4*>(rp+24);
      unsigned short* dp = T + ((size_t)(b*1024 + nbase + l))*1024 + obase + 32*h2;
      *reinterpret_cast<uint4*>(dp)    = r0;
      *reinterpret_cast<uint4*>(dp+8)  = r1;
      *reinterpret_cast<uint4*>(dp+16) = r2;
      *reinterpret_cast<uint4*>(dp+24) = r3;
    }
  } else {
    #pragma unroll
    for(int h2 = 0; h2 < 2; h2++){
      asm volatile("s_waitcnt lgkmcnt(0)" ::: "memory");
      __builtin_amdgcn_sched_barrier(0);
      #pragma unroll
      for(int nf2 = 0; nf2 < 2; nf2++){
        int nf = 2*h2 + nf2;
        #pragma unroll
        for(int mf = 0; mf < 4; mf++){
          int og = obase + 16*mf + 4*g;
          #pragma unroll
          for(int r = 0; r < 4; r++)
            scr[(16*mf + 4*g + r)*40 + 16*nf2 + ln] = bfn(acc[mf][nf][r] + bias[og+r]);
        }
      }
      asm volatile("s_waitcnt lgkmcnt(0)" ::: "memory");
      __builtin_amdgcn_sched_barrier(0);
      const unsigned short* rp = &scr[l*40];
      uint4 r0 = *reinterpret_cast<const uint4*>(rp);
      uint4 r1 = *reinterpret_cast<const uint4*>(rp+8);
      uint4 r2 = *reinterpret_cast<const uint4*>(rp+16);
      uint4 r3 = *reinterpret_cast<const uint4*>(rp+24);
      unsigned short* dp = V + ((size_t)(b*512 + obase - 1024 + l))*1024 + nbase + 32*h2;
      *reinterpret_cast<uint4*>(dp)    = r0;
      *reinterpret_cast<uint4*>(dp+8)  = r1;
      *reinterpret_cast<uint4*>(dp+16) = r2;
      *reinterpret_cast<uint4*>(dp+24) = r3;
    }
  }
}

// ---------------- Flash attention (r11/r15 measured-best): gload_lds staging,
// XOR-swizzled LDS, dbuf K+V, 1 barrier/tile, no-max exp2 softmax, Pl repack ----
__global__ __launch_bounds__(256) void attn_bf_k(const unsigned short* __restrict__ T,
                                                 const unsigned short* __restrict__ V,
                                                 unsigned short* __restrict__ attT){
  __shared__ __align__(16) unsigned short KT[2][64*64];
  __shared__ __align__(16) unsigned short Vt[2][64*64];
  __shared__ __align__(16) unsigned int   Pl[4*16*32];   // pitch 32 + XOR swizzle
  int tid = threadIdx.x;
  // XCD swizzle: all 16 n0-blocks of a head share id%8 (same XCD) -> K/V L2-resident
  int id = blockIdx.x;
  int bh = (id >> 7) * 8 + (id & 7);
  int n0 = ((id >> 3) & 15) * 64;
  int b = bh >> 3, h = bh & 7;
  int wq = tid >> 6, ln = tid & 15, g = (tid >> 4) & 3;
  int l = tid & 63;
  int nl = n0 + wq*16 + ln;                 // this lane's q-row
  const unsigned short* Tb = T + ((size_t)b << 20);
  bf16x8 qf0 = *reinterpret_cast<const bf16x8*>(Tb + (size_t)nl*1024 + h*64 + 8*g);
  bf16x8 qf1 = *reinterpret_cast<const bf16x8*>(Tb + (size_t)nl*1024 + h*64 + 32 + 8*g);
  f32x4 acc[4] = {};
  float l_part = 0.f;
  const unsigned short* kg = Tb + 512 + h*64;
  const unsigned short* vg = V + ((size_t)(b*512 + h*64))*1024;
  int pbase = wq*512 + ln*32;
  int psw = (ln & 7) << 2;                  // Pl word swizzle
  int swz  = (((l & 7) << 3) ^ ((l >> 3) << 3));
  const unsigned short* ksrc = kg + (size_t)(wq*16 + (l>>3))*1024 + swz;
  const unsigned short* vsrc = vg + (size_t)(wq*16 + (l>>3))*1024 + swz;
  int rsw = (ln & 7) << 3;
  int ro0 = (8*g) ^ rsw, ro1 = (32 + 8*g) ^ rsw;
  // prologue: stage tile 0 into buffer 0
  {
    unsigned short* kb = &KT[0][wq*16*64];
    unsigned short* vb = &Vt[0][wq*16*64];
    gl_lds16(ksrc,            kb);
    gl_lds16(ksrc + 8*1024,   kb + 8*64);
    gl_lds16(vsrc,            vb);
    gl_lds16(vsrc + 8*1024,   vb + 8*64);
  }
  __syncthreads();
  for(int t = 0; t < 16; t++){
    int buf = t & 1;
    if(t < 15){          // stage tile t+1 into the other buffer (hidden under compute)
      int m1 = (t + 1) * 64;
      unsigned short* kb = &KT[buf^1][wq*16*64];
      unsigned short* vb = &Vt[buf^1][wq*16*64];
      gl_lds16(ksrc + (size_t)m1*1024,          kb);
      gl_lds16(ksrc + (size_t)(m1+8)*1024,      kb + 8*64);
      gl_lds16(vsrc + m1,                       vb);
      gl_lds16(vsrc + 8*1024 + m1,              vb + 8*64);
    }
    // QK^T from swizzled KT[buf]
    f32x4 sf[4];
    #pragma unroll
    for(int mf = 0; mf < 4; mf++){
      bf16x8 a0 = *reinterpret_cast<const bf16x8*>(&KT[buf][(16*mf + ln)*64 + ro0]);
      bf16x8 a1 = *reinterpret_cast<const bf16x8*>(&KT[buf][(16*mf + ln)*64 + ro1]);
      f32x4 z = {0.f, 0.f, 0.f, 0.f};
      z = MFMA16(a0, qf0, z);
      sf[mf] = MFMA16(a1, qf1, z);
    }
    // p = exp2(s); per-lane l partial (no max tracking: scale cancels in the ratio)
    float p[16];
    #pragma unroll
    for(int mf = 0; mf < 4; mf++)
      #pragma unroll
      for(int r = 0; r < 4; r++){
        float v = EXP2(sf[mf][r]);
        p[mf*4 + r] = v;
        l_part += v;
      }
    // pack P (bf16 pairs) into per-wave LDS (XOR-swizzled), re-read as B-frags
    #pragma unroll
    for(int mt = 0; mt < 4; mt++){
      Pl[pbase + ((8*mt + 2*g + 0) ^ psw)] = pk2n(p[4*mt + 0], p[4*mt + 1]);
      Pl[pbase + ((8*mt + 2*g + 1) ^ psw)] = pk2n(p[4*mt + 2], p[4*mt + 3]);
    }
    asm volatile("s_waitcnt lgkmcnt(0)" ::: "memory");   // wave-local Pl ordering
    __builtin_amdgcn_sched_barrier(0);
    union { uint4 u; bf16x8 hv; } pb0, pb1;
    pb0.u = *reinterpret_cast<const uint4*>(&Pl[pbase + ((4*g) ^ psw)]);
    pb1.u = *reinterpret_cast<const uint4*>(&Pl[pbase + ((16 + 4*g) ^ psw)]);
    // PV from swizzled Vt[buf]
    #pragma unroll
    for(int cf = 0; cf < 4; cf++){
      bf16x8 v0 = *reinterpret_cast<const bf16x8*>(&Vt[buf][(16*cf + ln)*64 + ro0]);
      bf16x8 v1 = *reinterpret_cast<const bf16x8*>(&Vt[buf][(16*cf + ln)*64 + ro1]);
      acc[cf] = MFMA16(v0, pb0.hv, acc[cf]);
      acc[cf] = MFMA16(v1, pb1.hv, acc[cf]);
    }
    // one barrier per tile: drains staging (issued a full tile of compute ago)
    // and fences buffer reuse for the next iteration
    __syncthreads();
  }
  float lsum = l_part;
  lsum += __shfl_xor(lsum, 16);
  lsum += __shfl_xor(lsum, 32);
  float inv = 1.f / lsum;
  unsigned short* op = attT + ((size_t)(b*1024 + nl))*512 + h*64;
  #pragma unroll
  for(int cf = 0; cf < 4; cf++){
    uint2 pr;
    pr.x = pk2n(acc[cf][0]*inv, acc[cf][1]*inv);
    pr.y = pk2n(acc[cf][2]*inv, acc[cf][3]*inv);
    *reinterpret_cast<uint2*>(op + 16*cf + 4*g) = pr;
  }
}

// ---------------- proj GEMM (bf16 A and B, BK=64 dbuf counted-vmcnt) + bias + residual ----------------
__global__ __launch_bounds__(256) void proj_mm(const unsigned short* __restrict__ A,
                                               const unsigned short* __restrict__ Bx,
                                               const float* __restrict__ bias,
                                               const float* __restrict__ resid,
                                               float* __restrict__ out){
  __shared__ __align__(16) unsigned short As[2][128*64], Bs[2][128*64];
  int tid = threadIdx.x;
  int n0 = blockIdx.x*128, o0 = blockIdx.y*128, b = blockIdx.z;
  int wid = tid >> 6, wr = wid >> 1, wc = wid & 1, ln = tid & 15, g = (tid >> 4) & 3;
  int l = tid & 63;
  int rsw = (ln & 7) << 3;
  int srow = 32*wid + (l >> 3);
  int scol = (((l & 7) ^ (l >> 3)) << 3);
  const unsigned short* Ag = A  + (size_t)(o0 + srow)*512 + scol;
  const unsigned short* Bg = Bx + ((size_t)(b*1024 + n0 + srow))*512 + scol;
  f32x4 acc[4][4] = {};
  #pragma unroll
  for(int c = 0; c < 4; c++){
    gl_lds16(Ag + (size_t)(8*c)*512, &As[0][(32*wid + 8*c)*64]);
    gl_lds16(Bg + (size_t)(8*c)*512, &Bs[0][(32*wid + 8*c)*64]);
  }
  for(int t = 0; t < 8; t++){
    int buf = t & 1;
    if(t < 7){
      int k1 = (t + 1) * 64;
      #pragma unroll
      for(int c = 0; c < 4; c++){
        gl_lds16(Ag + (size_t)(8*c)*512 + k1, &As[buf^1][(32*wid + 8*c)*64]);
        gl_lds16(Bg + (size_t)(8*c)*512 + k1, &Bs[buf^1][(32*wid + 8*c)*64]);
      }
      asm volatile("s_waitcnt vmcnt(8)" ::: "memory");
    } else {
      asm volatile("s_waitcnt vmcnt(0)" ::: "memory");
    }
    __builtin_amdgcn_sched_barrier(0);
    __builtin_amdgcn_s_barrier();
    __builtin_amdgcn_sched_barrier(0);
    #pragma unroll
    for(int kh = 0; kh < 2; kh++){
      int ro = (kh*32 + 8*g) ^ rsw;
      bf16x8 af[4], bfv[4];
      #pragma unroll
      for(int mf = 0; mf < 4; mf++)
        af[mf] = *reinterpret_cast<const bf16x8*>(&As[buf][(wr*64 + 16*mf + ln)*64 + ro]);
      #pragma unroll
      for(int nf = 0; nf < 4; nf++)
        bfv[nf] = *reinterpret_cast<const bf16x8*>(&Bs[buf][(wc*64 + 16*nf + ln)*64 + ro]);
      #pragma unroll
      for(int mf = 0; mf < 4; mf++)
        #pragma unroll
        for(int nf = 0; nf < 4; nf++)
          acc[mf][nf] = MFMA16(af[mf], bfv[nf], acc[mf][nf]);
    }
    __builtin_amdgcn_sched_barrier(0);
    __builtin_amdgcn_s_barrier();
  }
  #pragma unroll
  for(int mf = 0; mf < 4; mf++)
    #pragma unroll
    for(int r = 0; r < 4; r++){
      int o = o0 + wr*64 + 16*mf + 4*g + r;
      float bo = bias[o];
      #pragma unroll
      for(int nf = 0; nf < 4; nf++){
        int n = n0 + wc*64 + 16*nf + ln;
        size_t off = ((size_t)(b*512 + o))*1024 + n;
        out[off] = acc[mf][nf][r] + bo + resid[off];
      }
    }
}

extern "C" void kernel_launch(void* const* d_in, const int* in_sizes, int n_in,
                              void* d_out, int out_size, void* d_ws, size_t ws_size,
                              hipStream_t stream){
  const float* x     = (const float*)d_in[0];
  const float* gnw   = (const float*)d_in[1];
  const float* gnb   = (const float*)d_in[2];
  const float* qkvw  = (const float*)d_in[3];
  const float* qkvb  = (const float*)d_in[4];
  const float* projw = (const float*)d_in[5];
  const float* projb = (const float*)d_in[6];
  float* out = (float*)d_out;

  char* w = (char*)d_ws;
  unsigned short* wqb = (unsigned short*)w;  w += (size_t)1536*512*2;
  unsigned short* wpb = (unsigned short*)w;  w += (size_t)512*512*2;
  unsigned short* xnT = (unsigned short*)w;  w += (size_t)16*1024*512*2;
  unsigned short* Tqk = (unsigned short*)w;  w += (size_t)16*1024*1024*2;
  unsigned short* Vb  = (unsigned short*)w;  w += (size_t)16*512*1024*2;
  unsigned short* attT = (unsigned short*)w; w += (size_t)16*1024*512*2;

  hipLaunchKernelGGL(pre_k, dim3(384), dim3(512), 0, stream,
                     x, gnw, gnb, xnT, qkvw, projw,
                     (unsigned int*)wqb, (unsigned int*)wpb);
  hipLaunchKernelGGL(qkv_mm, dim3(8, 12, 16), dim3(256), 0, stream, wqb, xnT, qkvb, Tqk, Vb);
  hipLaunchKernelGGL(attn_bf_k, dim3(2048), dim3(256), 0, stream, Tqk, Vb, attT);
  hipLaunchKernelGGL(proj_mm, dim3(8, 4, 16), dim3(256), 0, stream, wpb, attT, projb, x, out);
}

// Round 19
// 144.418 us; speedup vs baseline: 1.4887x; 1.0233x over previous
//
#include <hip/hip_runtime.h>
#include <hip/hip_bf16.h>
#include <math.h>

typedef short bf16x8 __attribute__((ext_vector_type(8)));
typedef float f32x4  __attribute__((ext_vector_type(4)));
#define MFMA16(a,b,c) __builtin_amdgcn_mfma_f32_16x16x32_bf16(a,b,c,0,0,0)

#define EPSF 1e-5f
#define QSC 0.18033688f   // 0.125 * log2(e), folded into Q

#if __has_builtin(__builtin_amdgcn_exp2f)
#define EXP2(x) __builtin_amdgcn_exp2f(x)
#else
#define EXP2(x) exp2f(x)
#endif

__device__ __forceinline__ unsigned int pk2n(float a, float b){
  __hip_bfloat162 h = __float22bfloat162_rn(make_float2(a, b));
  return *reinterpret_cast<unsigned int*>(&h);
}
__device__ __forceinline__ unsigned short bfn(float f){
  __hip_bfloat16 h = __float2bfloat16(f);
  return *reinterpret_cast<unsigned short*>(&h);
}
__device__ __forceinline__ float4 ld4(const float* p){ return *reinterpret_cast<const float4*>(p); }

// async global->LDS, 16B per lane; LDS dest = wave-uniform base + lane*16
__device__ __forceinline__ void gl_lds16(const unsigned short* g, unsigned short* l){
  __builtin_amdgcn_global_load_lds(
      (const __attribute__((address_space(1))) unsigned int*)g,
      (__attribute__((address_space(3))) unsigned int*)l, 16, 0, 0);
}

// ---------------- preamble: fused GroupNorm (blocks 0..127) + weight cvt (blocks 128..383) ----------------
__global__ __launch_bounds__(512) void pre_k(const float* __restrict__ x,
                                             const float* __restrict__ gnw,
                                             const float* __restrict__ gnb,
                                             unsigned short* __restrict__ xnT,
                                             const float* __restrict__ qkvw,
                                             const float* __restrict__ projw,
                                             unsigned int* __restrict__ wqb,
                                             unsigned int* __restrict__ wpb){
  __shared__ float Xl[2][64*65];
  __shared__ float red[16];
  int blk = blockIdx.x;
  int tid = threadIdx.x;
  if(blk >= 128){
    const float* src; unsigned int* dst; int base;
    if(blk < 320){ src = qkvw; dst = wqb; base = 128; }
    else         { src = projw; dst = wpb; base = 320; }
    int i = (blk - base)*1024 + tid*2;
    #pragma unroll
    for(int j = 0; j < 2; j++){
      float4 v = reinterpret_cast<const float4*>(src)[i + j];
      uint2 r; r.x = pk2n(v.x, v.y); r.y = pk2n(v.z, v.w);
      reinterpret_cast<uint2*>(dst)[i + j] = r;
    }
    return;
  }
  int b = blk >> 3, g = blk & 7;
  const float4* p4 = reinterpret_cast<const float4*>(x + (size_t)blk * 65536);
  float s1 = 0.f, s2 = 0.f;
  for(int i = tid; i < 16384; i += 512){
    float4 v = p4[i];
    s1 += (v.x + v.y) + (v.z + v.w);
    s2 += v.x*v.x + v.y*v.y + v.z*v.z + v.w*v.w;
  }
  #pragma unroll
  for(int off = 32; off; off >>= 1){ s1 += __shfl_xor(s1, off); s2 += __shfl_xor(s2, off); }
  if((tid & 63) == 0){ red[tid >> 6] = s1; red[8 + (tid >> 6)] = s2; }
  __syncthreads();
  float a = 0.f, b2 = 0.f;
  #pragma unroll
  for(int w = 0; w < 8; w++){ a += red[w]; b2 += red[8 + w]; }
  float mean = a * (1.f / 65536.f);
  float rstd = rsqrtf(b2 * (1.f / 65536.f) - mean * mean + EPSF);
  int half = tid >> 8, t256 = tid & 255;
  int nq = t256 & 15, rr = t256 >> 4;
  int c0 = g * 64;
  for(int it = 0; it < 8; it++){
    int n0 = (it*2 + half) * 64;
    __syncthreads();
    #pragma unroll
    for(int p = 0; p < 4; p++){
      int cl = p * 16 + rr, c = c0 + cl;
      float s = rstd * gnw[c], t = gnb[c] - mean * s;
      float4 v = ld4(x + ((size_t)(b*512 + c))*1024 + n0 + 4*nq);
      Xl[half][(4*nq+0)*65 + cl] = v.x*s + t;
      Xl[half][(4*nq+1)*65 + cl] = v.y*s + t;
      Xl[half][(4*nq+2)*65 + cl] = v.z*s + t;
      Xl[half][(4*nq+3)*65 + cl] = v.w*s + t;
    }
    __syncthreads();
    int n = t256 >> 2, cq = t256 & 3;
    float f[16];
    #pragma unroll
    for(int k = 0; k < 16; k++) f[k] = Xl[half][n*65 + 16*cq + k];
    uint4 w0, w1;
    w0.x = pk2n(f[0],f[1]);  w0.y = pk2n(f[2],f[3]);  w0.z = pk2n(f[4],f[5]);  w0.w = pk2n(f[6],f[7]);
    w1.x = pk2n(f[8],f[9]);  w1.y = pk2n(f[10],f[11]);w1.z = pk2n(f[12],f[13]);w1.w = pk2n(f[14],f[15]);
    unsigned short* dp = xnT + ((size_t)(b*1024 + n0 + n))*512 + c0 + 16*cq;
    *reinterpret_cast<uint4*>(dp)     = w0;
    *reinterpret_cast<uint4*>(dp + 8) = w1;
  }
}

// ---- GEMM core: BK=64 DOUBLE-buffered, counted vmcnt(8) + raw s_barrier (T4),
// gl_lds staging, XOR-swizzled linear LDS (r15 measured-best). ----

// ---------------- QKV GEMM: Q,K transposed (Q pre-scaled) + V natural ----------------
__global__ __launch_bounds__(256) void qkv_mm(const unsigned short* __restrict__ A,
                                              const unsigned short* __restrict__ Bx,
                                              const float* __restrict__ bias,
                                              unsigned short* __restrict__ T,
                                              unsigned short* __restrict__ V){
  __shared__ __align__(16) unsigned short As[2][128*64], Bs[2][128*64];
  int tid = threadIdx.x;
  int n0 = blockIdx.x*128, o0 = blockIdx.y*128, b = blockIdx.z;
  int wid = tid >> 6, wr = wid >> 1, wc = wid & 1, ln = tid & 15, g = (tid >> 4) & 3;
  int l = tid & 63;
  int rsw = (ln & 7) << 3;
  int srow = 32*wid + (l >> 3);
  int scol = (((l & 7) ^ (l >> 3)) << 3);
  const unsigned short* Ag = A  + (size_t)(o0 + srow)*512 + scol;
  const unsigned short* Bg = Bx + ((size_t)(b*1024 + n0 + srow))*512 + scol;
  f32x4 acc[4][4] = {};
  #pragma unroll
  for(int c = 0; c < 4; c++){
    gl_lds16(Ag + (size_t)(8*c)*512, &As[0][(32*wid + 8*c)*64]);
    gl_lds16(Bg + (size_t)(8*c)*512, &Bs[0][(32*wid + 8*c)*64]);
  }
  for(int t = 0; t < 8; t++){
    int buf = t & 1;
    if(t < 7){
      int k1 = (t + 1) * 64;
      #pragma unroll
      for(int c = 0; c < 4; c++){
        gl_lds16(Ag + (size_t)(8*c)*512 + k1, &As[buf^1][(32*wid + 8*c)*64]);
        gl_lds16(Bg + (size_t)(8*c)*512 + k1, &Bs[buf^1][(32*wid + 8*c)*64]);
      }
      asm volatile("s_waitcnt vmcnt(8)" ::: "memory");   // tile t's 8 loads done
    } else {
      asm volatile("s_waitcnt vmcnt(0)" ::: "memory");
    }
    __builtin_amdgcn_sched_barrier(0);
    __builtin_amdgcn_s_barrier();
    __builtin_amdgcn_sched_barrier(0);
    #pragma unroll
    for(int kh = 0; kh < 2; kh++){
      int ro = (kh*32 + 8*g) ^ rsw;
      bf16x8 af[4], bfv[4];
      #pragma unroll
      for(int mf = 0; mf < 4; mf++)
        af[mf] = *reinterpret_cast<const bf16x8*>(&As[buf][(wr*64 + 16*mf + ln)*64 + ro]);
      #pragma unroll
      for(int nf = 0; nf < 4; nf++)
        bfv[nf] = *reinterpret_cast<const bf16x8*>(&Bs[buf][(wc*64 + 16*nf + ln)*64 + ro]);
      #pragma unroll
      for(int mf = 0; mf < 4; mf++)
        #pragma unroll
        for(int nf = 0; nf < 4; nf++)
          acc[mf][nf] = MFMA16(af[mf], bfv[nf], acc[mf][nf]);
    }
    __builtin_amdgcn_sched_barrier(0);
    __builtin_amdgcn_s_barrier();
  }
  int obase = o0 + wr*64, nbase = n0 + wc*64;
  unsigned short* scr = &As[0][0] + wid * 2560;          // 64 rows x 40 pitch, per-wave scratch
  float sc = (obase < 512) ? QSC : 1.0f;
  if(obase < 1024){
    #pragma unroll
    for(int h2 = 0; h2 < 2; h2++){
      asm volatile("s_waitcnt lgkmcnt(0)" ::: "memory");
      __builtin_amdgcn_sched_barrier(0);
      #pragma unroll
      for(int mf2 = 0; mf2 < 2; mf2++){
        int mf = 2*h2 + mf2;
        int og = obase + 16*mf + 4*g;
        float b0 = bias[og], b1 = bias[og+1], b2 = bias[og+2], b3 = bias[og+3];
        #pragma unroll
        for(int nf = 0; nf < 4; nf++){
          uint2 pr;
          pr.x = pk2n((acc[mf][nf][0]+b0)*sc, (acc[mf][nf][1]+b1)*sc);
          pr.y = pk2n((acc[mf][nf][2]+b2)*sc, (acc[mf][nf][3]+b3)*sc);
          *reinterpret_cast<uint2*>(&scr[(16*nf + ln)*40 + 16*mf2 + 4*g]) = pr;
        }
      }
      asm volatile("s_waitcnt lgkmcnt(0)" ::: "memory");
      __builtin_amdgcn_sched_barrier(0);
      const unsigned short* rp = &scr[l*40];
      uint4 r0 = *reinterpret_cast<const uint4*>(rp);
      uint4 r1 = *reinterpret_cast<const uint4*>(rp+8);
      uint4 r2 = *reinterpret_cast<const uint4*>(rp+16);
      uint4 r3 = *reinterpret_cast<const uint4*>(rp+24);
      unsigned short* dp = T + ((size_t)(b*1024 + nbase + l))*1024 + obase + 32*h2;
      *reinterpret_cast<uint4*>(dp)    = r0;
      *reinterpret_cast<uint4*>(dp+8)  = r1;
      *reinterpret_cast<uint4*>(dp+16) = r2;
      *reinterpret_cast<uint4*>(dp+24) = r3;
    }
  } else {
    #pragma unroll
    for(int h2 = 0; h2 < 2; h2++){
      asm volatile("s_waitcnt lgkmcnt(0)" ::: "memory");
      __builtin_amdgcn_sched_barrier(0);
      #pragma unroll
      for(int nf2 = 0; nf2 < 2; nf2++){
        int nf = 2*h2 + nf2;
        #pragma unroll
        for(int mf = 0; mf < 4; mf++){
          int og = obase + 16*mf + 4*g;
          #pragma unroll
          for(int r = 0; r < 4; r++)
            scr[(16*mf + 4*g + r)*40 + 16*nf2 + ln] = bfn(acc[mf][nf][r] + bias[og+r]);
        }
      }
      asm volatile("s_waitcnt lgkmcnt(0)" ::: "memory");
      __builtin_amdgcn_sched_barrier(0);
      const unsigned short* rp = &scr[l*40];
      uint4 r0 = *reinterpret_cast<const uint4*>(rp);
      uint4 r1 = *reinterpret_cast<const uint4*>(rp+8);
      uint4 r2 = *reinterpret_cast<const uint4*>(rp+16);
      uint4 r3 = *reinterpret_cast<const uint4*>(rp+24);
      unsigned short* dp = V + ((size_t)(b*512 + obase - 1024 + l))*1024 + nbase + 32*h2;
      *reinterpret_cast<uint4*>(dp)    = r0;
      *reinterpret_cast<uint4*>(dp+8)  = r1;
      *reinterpret_cast<uint4*>(dp+16) = r2;
      *reinterpret_cast<uint4*>(dp+24) = r3;
    }
  }
}

// ---------------- Flash attention: SINGLE-buffer K (8 KB) + dbuf V (16 KB) + Pl (8 KB)
// = 32 KB -> 5 blocks/CU. Two raw barriers/tile with counted vmcnt so staging stays
// in flight: [K(t+1),V(t+1)] issued after QK-barrier; vmcnt(4) before PV retires V(t);
// vmcnt(2) before bottom barrier retires K(t+1). ----------------
__global__ __launch_bounds__(256) void attn_bf_k(const unsigned short* __restrict__ T,
                                                 const unsigned short* __restrict__ V,
                                                 unsigned short* __restrict__ attT){
  __shared__ __align__(16) unsigned short KT[64*64];
  __shared__ __align__(16) unsigned short Vt[2][64*64];
  __shared__ __align__(16) unsigned int   Pl[4*16*32];   // pitch 32 + XOR swizzle
  int tid = threadIdx.x;
  // XCD swizzle: all 16 n0-blocks of a head share id%8 (same XCD) -> K/V L2-resident
  int id = blockIdx.x;
  int bh = (id >> 7) * 8 + (id & 7);
  int n0 = ((id >> 3) & 15) * 64;
  int b = bh >> 3, h = bh & 7;
  int wq = tid >> 6, ln = tid & 15, g = (tid >> 4) & 3;
  int l = tid & 63;
  int nl = n0 + wq*16 + ln;                 // this lane's q-row
  const unsigned short* Tb = T + ((size_t)b << 20);
  bf16x8 qf0 = *reinterpret_cast<const bf16x8*>(Tb + (size_t)nl*1024 + h*64 + 8*g);
  bf16x8 qf1 = *reinterpret_cast<const bf16x8*>(Tb + (size_t)nl*1024 + h*64 + 32 + 8*g);
  f32x4 acc[4] = {};
  float l_part = 0.f;
  const unsigned short* kg = Tb + 512 + h*64;
  const unsigned short* vg = V + ((size_t)(b*512 + h*64))*1024;
  int pbase = wq*512 + ln*32;
  int psw = (ln & 7) << 2;                  // Pl word swizzle
  int swz  = (((l & 7) << 3) ^ ((l >> 3) << 3));
  const unsigned short* ksrc = kg + (size_t)(wq*16 + (l>>3))*1024 + swz;
  const unsigned short* vsrc = vg + (size_t)(wq*16 + (l>>3))*1024 + swz;
  int rsw = (ln & 7) << 3;
  int ro0 = (8*g) ^ rsw, ro1 = (32 + 8*g) ^ rsw;
  // prologue: stage K(0) and V(0)
  {
    unsigned short* kb = &KT[wq*16*64];
    unsigned short* vb = &Vt[0][wq*16*64];
    gl_lds16(ksrc,            kb);
    gl_lds16(ksrc + 8*1024,   kb + 8*64);
    gl_lds16(vsrc,            vb);
    gl_lds16(vsrc + 8*1024,   vb + 8*64);
  }
  __syncthreads();
  for(int t = 0; t < 16; t++){
    int buf = t & 1;
    // QK^T from single-buffer KT
    f32x4 sf[4];
    #pragma unroll
    for(int mf = 0; mf < 4; mf++){
      bf16x8 a0 = *reinterpret_cast<const bf16x8*>(&KT[(16*mf + ln)*64 + ro0]);
      bf16x8 a1 = *reinterpret_cast<const bf16x8*>(&KT[(16*mf + ln)*64 + ro1]);
      f32x4 z = {0.f, 0.f, 0.f, 0.f};
      z = MFMA16(a0, qf0, z);
      sf[mf] = MFMA16(a1, qf1, z);
    }
    if(t < 15){
      // barrier A: all waves finished reading KT -> safe to overwrite
      __builtin_amdgcn_sched_barrier(0);
      __builtin_amdgcn_s_barrier();
      __builtin_amdgcn_sched_barrier(0);
      int m1 = (t + 1) * 64;
      unsigned short* kb = &KT[wq*16*64];
      unsigned short* vb = &Vt[buf^1][wq*16*64];
      gl_lds16(ksrc + (size_t)m1*1024,          kb);        // K(t+1) first (FIFO)
      gl_lds16(ksrc + (size_t)(m1+8)*1024,      kb + 8*64);
      gl_lds16(vsrc + m1,                       vb);        // then V(t+1)
      gl_lds16(vsrc + 8*1024 + m1,              vb + 8*64);
    }
    // p = exp2(s); per-lane l partial (no max tracking: scale cancels in the ratio)
    float p[16];
    #pragma unroll
    for(int mf = 0; mf < 4; mf++)
      #pragma unroll
      for(int r = 0; r < 4; r++){
        float v = EXP2(sf[mf][r]);
        p[mf*4 + r] = v;
        l_part += v;
      }
    // pack P (bf16 pairs) into per-wave LDS (XOR-swizzled), re-read as B-frags
    #pragma unroll
    for(int mt = 0; mt < 4; mt++){
      Pl[pbase + ((8*mt + 2*g + 0) ^ psw)] = pk2n(p[4*mt + 0], p[4*mt + 1]);
      Pl[pbase + ((8*mt + 2*g + 1) ^ psw)] = pk2n(p[4*mt + 2], p[4*mt + 3]);
    }
    asm volatile("s_waitcnt lgkmcnt(0)" ::: "memory");   // wave-local Pl ordering
    __builtin_amdgcn_sched_barrier(0);
    union { uint4 u; bf16x8 hv; } pb0, pb1;
    pb0.u = *reinterpret_cast<const uint4*>(&Pl[pbase + ((4*g) ^ psw)]);
    pb1.u = *reinterpret_cast<const uint4*>(&Pl[pbase + ((16 + 4*g) ^ psw)]);
    // retire V(t) (older than the newest 4 in-flight staging ops); keep K/V(t+1) flying
    if(t < 15){
      asm volatile("s_waitcnt vmcnt(4)" ::: "memory");
    } else {
      asm volatile("s_waitcnt vmcnt(0)" ::: "memory");
    }
    __builtin_amdgcn_sched_barrier(0);
    // PV from swizzled Vt[buf]
    #pragma unroll
    for(int cf = 0; cf < 4; cf++){
      bf16x8 v0 = *reinterpret_cast<const bf16x8*>(&Vt[buf][(16*cf + ln)*64 + ro0]);
      bf16x8 v1 = *reinterpret_cast<const bf16x8*>(&Vt[buf][(16*cf + ln)*64 + ro1]);
      acc[cf] = MFMA16(v0, pb0.hv, acc[cf]);
      acc[cf] = MFMA16(v1, pb1.hv, acc[cf]);
    }
    if(t < 15){
      // barrier B: K(t+1) retired in every wave -> next QK safe; V(t+1) stays in flight
      __builtin_amdgcn_sched_barrier(0);
      asm volatile("s_waitcnt vmcnt(2)" ::: "memory");
      __builtin_amdgcn_sched_barrier(0);
      __builtin_amdgcn_s_barrier();
    }
  }
  float lsum = l_part;
  lsum += __shfl_xor(lsum, 16);
  lsum += __shfl_xor(lsum, 32);
  float inv = 1.f / lsum;
  unsigned short* op = attT + ((size_t)(b*1024 + nl))*512 + h*64;
  #pragma unroll
  for(int cf = 0; cf < 4; cf++){
    uint2 pr;
    pr.x = pk2n(acc[cf][0]*inv, acc[cf][1]*inv);
    pr.y = pk2n(acc[cf][2]*inv, acc[cf][3]*inv);
    *reinterpret_cast<uint2*>(op + 16*cf + 4*g) = pr;
  }
}

// ---------------- proj GEMM (bf16 A and B, BK=64 dbuf counted-vmcnt) + bias + residual ----------------
__global__ __launch_bounds__(256) void proj_mm(const unsigned short* __restrict__ A,
                                               const unsigned short* __restrict__ Bx,
                                               const float* __restrict__ bias,
                                               const float* __restrict__ resid,
                                               float* __restrict__ out){
  __shared__ __align__(16) unsigned short As[2][128*64], Bs[2][128*64];
  int tid = threadIdx.x;
  int n0 = blockIdx.x*128, o0 = blockIdx.y*128, b = blockIdx.z;
  int wid = tid >> 6, wr = wid >> 1, wc = wid & 1, ln = tid & 15, g = (tid >> 4) & 3;
  int l = tid & 63;
  int rsw = (ln & 7) << 3;
  int srow = 32*wid + (l >> 3);
  int scol = (((l & 7) ^ (l >> 3)) << 3);
  const unsigned short* Ag = A  + (size_t)(o0 + srow)*512 + scol;
  const unsigned short* Bg = Bx + ((size_t)(b*1024 + n0 + srow))*512 + scol;
  f32x4 acc[4][4] = {};
  #pragma unroll
  for(int c = 0; c < 4; c++){
    gl_lds16(Ag + (size_t)(8*c)*512, &As[0][(32*wid + 8*c)*64]);
    gl_lds16(Bg + (size_t)(8*c)*512, &Bs[0][(32*wid + 8*c)*64]);
  }
  for(int t = 0; t < 8; t++){
    int buf = t & 1;
    if(t < 7){
      int k1 = (t + 1) * 64;
      #pragma unroll
      for(int c = 0; c < 4; c++){
        gl_lds16(Ag + (size_t)(8*c)*512 + k1, &As[buf^1][(32*wid + 8*c)*64]);
        gl_lds16(Bg + (size_t)(8*c)*512 + k1, &Bs[buf^1][(32*wid + 8*c)*64]);
      }
      asm volatile("s_waitcnt vmcnt(8)" ::: "memory");
    } else {
      asm volatile("s_waitcnt vmcnt(0)" ::: "memory");
    }
    __builtin_amdgcn_sched_barrier(0);
    __builtin_amdgcn_s_barrier();
    __builtin_amdgcn_sched_barrier(0);
    #pragma unroll
    for(int kh = 0; kh < 2; kh++){
      int ro = (kh*32 + 8*g) ^ rsw;
      bf16x8 af[4], bfv[4];
      #pragma unroll
      for(int mf = 0; mf < 4; mf++)
        af[mf] = *reinterpret_cast<const bf16x8*>(&As[buf][(wr*64 + 16*mf + ln)*64 + ro]);
      #pragma unroll
      for(int nf = 0; nf < 4; nf++)
        bfv[nf] = *reinterpret_cast<const bf16x8*>(&Bs[buf][(wc*64 + 16*nf + ln)*64 + ro]);
      #pragma unroll
      for(int mf = 0; mf < 4; mf++)
        #pragma unroll
        for(int nf = 0; nf < 4; nf++)
          acc[mf][nf] = MFMA16(af[mf], bfv[nf], acc[mf][nf]);
    }
    __builtin_amdgcn_sched_barrier(0);
    __builtin_amdgcn_s_barrier();
  }
  #pragma unroll
  for(int mf = 0; mf < 4; mf++)
    #pragma unroll
    for(int r = 0; r < 4; r++){
      int o = o0 + wr*64 + 16*mf + 4*g + r;
      float bo = bias[o];
      #pragma unroll
      for(int nf = 0; nf < 4; nf++){
        int n = n0 + wc*64 + 16*nf + ln;
        size_t off = ((size_t)(b*512 + o))*1024 + n;
        out[off] = acc[mf][nf][r] + bo + resid[off];
      }
    }
}

extern "C" void kernel_launch(void* const* d_in, const int* in_sizes, int n_in,
                              void* d_out, int out_size, void* d_ws, size_t ws_size,
                              hipStream_t stream){
  const float* x     = (const float*)d_in[0];
  const float* gnw   = (const float*)d_in[1];
  const float* gnb   = (const float*)d_in[2];
  const float* qkvw  = (const float*)d_in[3];
  const float* qkvb  = (const float*)d_in[4];
  const float* projw = (const float*)d_in[5];
  const float* projb = (const float*)d_in[6];
  float* out = (float*)d_out;

  char* w = (char*)d_ws;
  unsigned short* wqb = (unsigned short*)w;  w += (size_t)1536*512*2;
  unsigned short* wpb = (unsigned short*)w;  w += (size_t)512*512*2;
  unsigned short* xnT = (unsigned short*)w;  w += (size_t)16*1024*512*2;
  unsigned short* Tqk = (unsigned short*)w;  w += (size_t)16*1024*1024*2;
  unsigned short* Vb  = (unsigned short*)w;  w += (size_t)16*512*1024*2;
  unsigned short* attT = (unsigned short*)w; w += (size_t)16*1024*512*2;

  hipLaunchKernelGGL(pre_k, dim3(384), dim3(512), 0, stream,
                     x, gnw, gnb, xnT, qkvw, projw,
                     (unsigned int*)wqb, (unsigned int*)wpb);
  hipLaunchKernelGGL(qkv_mm, dim3(8, 12, 16), dim3(256), 0, stream, wqb, xnT, qkvb, Tqk, Vb);
  hipLaunchKernelGGL(attn_bf_k, dim3(2048), dim3(256), 0, stream, Tqk, Vb, attT);
  hipLaunchKernelGGL(proj_mm, dim3(8, 4, 16), dim3(256), 0, stream, wpb, attT, projb, x, out);
}

// Round 20
// 137.379 us; speedup vs baseline: 1.5649x; 1.0512x over previous
//
#include <hip/hip_runtime.h>
#include <hip/hip_bf16.h>
#include <math.h>

typedef short bf16x8 __attribute__((ext_vector_type(8)));
typedef float f32x4  __attribute__((ext_vector_type(4)));
typedef float f32x16 __attribute__((ext_vector_type(16)));
typedef unsigned int uintx2 __attribute__((ext_vector_type(2)));
#define MFMA16(a,b,c) __builtin_amdgcn_mfma_f32_16x16x32_bf16(a,b,c,0,0,0)
#define MFMA32(a,b,c) __builtin_amdgcn_mfma_f32_32x32x16_bf16(a,b,c,0,0,0)

#define EPSF 1e-5f
#define QSC 0.18033688f   // 0.125 * log2(e), folded into Q

#if __has_builtin(__builtin_amdgcn_exp2f)
#define EXP2(x) __builtin_amdgcn_exp2f(x)
#else
#define EXP2(x) exp2f(x)
#endif

__device__ __forceinline__ unsigned int pk2n(float a, float b){
  __hip_bfloat162 h = __float22bfloat162_rn(make_float2(a, b));
  return *reinterpret_cast<unsigned int*>(&h);
}
__device__ __forceinline__ unsigned short bfn(float f){
  __hip_bfloat16 h = __float2bfloat16(f);
  return *reinterpret_cast<unsigned short*>(&h);
}
__device__ __forceinline__ float4 ld4(const float* p){ return *reinterpret_cast<const float4*>(p); }

// swap halves: r[0]: lane<32 keeps x, lane>=32 gets y from lane-32;
//              r[1]: lane<32 gets x from lane+32, lane>=32 keeps y.
__device__ __forceinline__ void plswap(unsigned int& x, unsigned int& y){
#if __has_builtin(__builtin_amdgcn_permlane32_swap)
  uintx2 r = __builtin_amdgcn_permlane32_swap(x, y, false, false);
  x = r[0]; y = r[1];
#else
  asm volatile("v_permlane32_swap_b32 %0, %1" : "+v"(x), "+v"(y));
#endif
}

// async global->LDS, 16B per lane; LDS dest = wave-uniform base + lane*16
__device__ __forceinline__ void gl_lds16(const unsigned short* g, unsigned short* l){
  __builtin_amdgcn_global_load_lds(
      (const __attribute__((address_space(1))) unsigned int*)g,
      (__attribute__((address_space(3))) unsigned int*)l, 16, 0, 0);
}

// ---------------- preamble: fused GroupNorm (blocks 0..127) + weight cvt (blocks 128..383) ----------------
__global__ __launch_bounds__(512) void pre_k(const float* __restrict__ x,
                                             const float* __restrict__ gnw,
                                             const float* __restrict__ gnb,
                                             unsigned short* __restrict__ xnT,
                                             const float* __restrict__ qkvw,
                                             const float* __restrict__ projw,
                                             unsigned int* __restrict__ wqb,
                                             unsigned int* __restrict__ wpb){
  __shared__ float Xl[2][64*65];
  __shared__ float red[16];
  int blk = blockIdx.x;
  int tid = threadIdx.x;
  if(blk >= 128){
    const float* src; unsigned int* dst; int base;
    if(blk < 320){ src = qkvw; dst = wqb; base = 128; }
    else         { src = projw; dst = wpb; base = 320; }
    int i = (blk - base)*1024 + tid*2;
    #pragma unroll
    for(int j = 0; j < 2; j++){
      float4 v = reinterpret_cast<const float4*>(src)[i + j];
      uint2 r; r.x = pk2n(v.x, v.y); r.y = pk2n(v.z, v.w);
      reinterpret_cast<uint2*>(dst)[i + j] = r;
    }
    return;
  }
  int b = blk >> 3, g = blk & 7;
  const float4* p4 = reinterpret_cast<const float4*>(x + (size_t)blk * 65536);
  float s1 = 0.f, s2 = 0.f;
  for(int i = tid; i < 16384; i += 512){
    float4 v = p4[i];
    s1 += (v.x + v.y) + (v.z + v.w);
    s2 += v.x*v.x + v.y*v.y + v.z*v.z + v.w*v.w;
  }
  #pragma unroll
  for(int off = 32; off; off >>= 1){ s1 += __shfl_xor(s1, off); s2 += __shfl_xor(s2, off); }
  if((tid & 63) == 0){ red[tid >> 6] = s1; red[8 + (tid >> 6)] = s2; }
  __syncthreads();
  float a = 0.f, b2 = 0.f;
  #pragma unroll
  for(int w = 0; w < 8; w++){ a += red[w]; b2 += red[8 + w]; }
  float mean = a * (1.f / 65536.f);
  float rstd = rsqrtf(b2 * (1.f / 65536.f) - mean * mean + EPSF);
  int half = tid >> 8, t256 = tid & 255;
  int nq = t256 & 15, rr = t256 >> 4;
  int c0 = g * 64;
  for(int it = 0; it < 8; it++){
    int n0 = (it*2 + half) * 64;
    __syncthreads();
    #pragma unroll
    for(int p = 0; p < 4; p++){
      int cl = p * 16 + rr, c = c0 + cl;
      float s = rstd * gnw[c], t = gnb[c] - mean * s;
      float4 v = ld4(x + ((size_t)(b*512 + c))*1024 + n0 + 4*nq);
      Xl[half][(4*nq+0)*65 + cl] = v.x*s + t;
      Xl[half][(4*nq+1)*65 + cl] = v.y*s + t;
      Xl[half][(4*nq+2)*65 + cl] = v.z*s + t;
      Xl[half][(4*nq+3)*65 + cl] = v.w*s + t;
    }
    __syncthreads();
    int n = t256 >> 2, cq = t256 & 3;
    float f[16];
    #pragma unroll
    for(int k = 0; k < 16; k++) f[k] = Xl[half][n*65 + 16*cq + k];
    uint4 w0, w1;
    w0.x = pk2n(f[0],f[1]);  w0.y = pk2n(f[2],f[3]);  w0.z = pk2n(f[4],f[5]);  w0.w = pk2n(f[6],f[7]);
    w1.x = pk2n(f[8],f[9]);  w1.y = pk2n(f[10],f[11]);w1.z = pk2n(f[12],f[13]);w1.w = pk2n(f[14],f[15]);
    unsigned short* dp = xnT + ((size_t)(b*1024 + n0 + n))*512 + c0 + 16*cq;
    *reinterpret_cast<uint4*>(dp)     = w0;
    *reinterpret_cast<uint4*>(dp + 8) = w1;
  }
}

// ---- GEMM core: BK=64 DOUBLE-buffered, counted vmcnt(8) + raw s_barrier (T4),
// gl_lds staging, XOR-swizzled linear LDS (r15 measured-best). ----

// ---------------- QKV GEMM: Q,K transposed (Q pre-scaled) + V natural ----------------
__global__ __launch_bounds__(256) void qkv_mm(const unsigned short* __restrict__ A,
                                              const unsigned short* __restrict__ Bx,
                                              const float* __restrict__ bias,
                                              unsigned short* __restrict__ T,
                                              unsigned short* __restrict__ V){
  __shared__ __align__(16) unsigned short As[2][128*64], Bs[2][128*64];
  int tid = threadIdx.x;
  int n0 = blockIdx.x*128, o0 = blockIdx.y*128, b = blockIdx.z;
  int wid = tid >> 6, wr = wid >> 1, wc = wid & 1, ln = tid & 15, g = (tid >> 4) & 3;
  int l = tid & 63;
  int rsw = (ln & 7) << 3;
  int srow = 32*wid + (l >> 3);
  int scol = (((l & 7) ^ (l >> 3)) << 3);
  const unsigned short* Ag = A  + (size_t)(o0 + srow)*512 + scol;
  const unsigned short* Bg = Bx + ((size_t)(b*1024 + n0 + srow))*512 + scol;
  f32x4 acc[4][4] = {};
  #pragma unroll
  for(int c = 0; c < 4; c++){
    gl_lds16(Ag + (size_t)(8*c)*512, &As[0][(32*wid + 8*c)*64]);
    gl_lds16(Bg + (size_t)(8*c)*512, &Bs[0][(32*wid + 8*c)*64]);
  }
  for(int t = 0; t < 8; t++){
    int buf = t & 1;
    if(t < 7){
      int k1 = (t + 1) * 64;
      #pragma unroll
      for(int c = 0; c < 4; c++){
        gl_lds16(Ag + (size_t)(8*c)*512 + k1, &As[buf^1][(32*wid + 8*c)*64]);
        gl_lds16(Bg + (size_t)(8*c)*512 + k1, &Bs[buf^1][(32*wid + 8*c)*64]);
      }
      asm volatile("s_waitcnt vmcnt(8)" ::: "memory");   // tile t's 8 loads done
    } else {
      asm volatile("s_waitcnt vmcnt(0)" ::: "memory");
    }
    __builtin_amdgcn_sched_barrier(0);
    __builtin_amdgcn_s_barrier();
    __builtin_amdgcn_sched_barrier(0);
    #pragma unroll
    for(int kh = 0; kh < 2; kh++){
      int ro = (kh*32 + 8*g) ^ rsw;
      bf16x8 af[4], bfv[4];
      #pragma unroll
      for(int mf = 0; mf < 4; mf++)
        af[mf] = *reinterpret_cast<const bf16x8*>(&As[buf][(wr*64 + 16*mf + ln)*64 + ro]);
      #pragma unroll
      for(int nf = 0; nf < 4; nf++)
        bfv[nf] = *reinterpret_cast<const bf16x8*>(&Bs[buf][(wc*64 + 16*nf + ln)*64 + ro]);
      #pragma unroll
      for(int mf = 0; mf < 4; mf++)
        #pragma unroll
        for(int nf = 0; nf < 4; nf++)
          acc[mf][nf] = MFMA16(af[mf], bfv[nf], acc[mf][nf]);
    }
    __builtin_amdgcn_sched_barrier(0);
    __builtin_amdgcn_s_barrier();
  }
  int obase = o0 + wr*64, nbase = n0 + wc*64;
  unsigned short* scr = &As[0][0] + wid * 2560;          // 64 rows x 40 pitch, per-wave scratch
  float sc = (obase < 512) ? QSC : 1.0f;
  if(obase < 1024){
    #pragma unroll
    for(int h2 = 0; h2 < 2; h2++){
      asm volatile("s_waitcnt lgkmcnt(0)" ::: "memory");
      __builtin_amdgcn_sched_barrier(0);
      #pragma unroll
      for(int mf2 = 0; mf2 < 2; mf2++){
        int mf = 2*h2 + mf2;
        int og = obase + 16*mf + 4*g;
        float b0 = bias[og], b1 = bias[og+1], b2 = bias[og+2], b3 = bias[og+3];
        #pragma unroll
        for(int nf = 0; nf < 4; nf++){
          uint2 pr;
          pr.x = pk2n((acc[mf][nf][0]+b0)*sc, (acc[mf][nf][1]+b1)*sc);
          pr.y = pk2n((acc[mf][nf][2]+b2)*sc, (acc[mf][nf][3]+b3)*sc);
          *reinterpret_cast<uint2*>(&scr[(16*nf + ln)*40 + 16*mf2 + 4*g]) = pr;
        }
      }
      asm volatile("s_waitcnt lgkmcnt(0)" ::: "memory");
      __builtin_amdgcn_sched_barrier(0);
      const unsigned short* rp = &scr[l*40];
      uint4 r0 = *reinterpret_cast<const uint4*>(rp);
      uint4 r1 = *reinterpret_cast<const uint4*>(rp+8);
      uint4 r2 = *reinterpret_cast<const uint4*>(rp+16);
      uint4 r3 = *reinterpret_cast<const uint4*>(rp+24);
      unsigned short* dp = T + ((size_t)(b*1024 + nbase + l))*1024 + obase + 32*h2;
      *reinterpret_cast<uint4*>(dp)    = r0;
      *reinterpret_cast<uint4*>(dp+8)  = r1;
      *reinterpret_cast<uint4*>(dp+16) = r2;
      *reinterpret_cast<uint4*>(dp+24) = r3;
    }
  } else {
    #pragma unroll
    for(int h2 = 0; h2 < 2; h2++){
      asm volatile("s_waitcnt lgkmcnt(0)" ::: "memory");
      __builtin_amdgcn_sched_barrier(0);
      #pragma unroll
      for(int nf2 = 0; nf2 < 2; nf2++){
        int nf = 2*h2 + nf2;
        #pragma unroll
        for(int mf = 0; mf < 4; mf++){
          int og = obase + 16*mf + 4*g;
          #pragma unroll
          for(int r = 0; r < 4; r++)
            scr[(16*mf + 4*g + r)*40 + 16*nf2 + ln] = bfn(acc[mf][nf][r] + bias[og+r]);
        }
      }
      asm volatile("s_waitcnt lgkmcnt(0)" ::: "memory");
      __builtin_amdgcn_sched_barrier(0);
      const unsigned short* rp = &scr[l*40];
      uint4 r0 = *reinterpret_cast<const uint4*>(rp);
      uint4 r1 = *reinterpret_cast<const uint4*>(rp+8);
      uint4 r2 = *reinterpret_cast<const uint4*>(rp+16);
      uint4 r3 = *reinterpret_cast<const uint4*>(rp+24);
      unsigned short* dp = V + ((size_t)(b*512 + obase - 1024 + l))*1024 + nbase + 32*h2;
      *reinterpret_cast<uint4*>(dp)    = r0;
      *reinterpret_cast<uint4*>(dp+8)  = r1;
      *reinterpret_cast<uint4*>(dp+16) = r2;
      *reinterpret_cast<uint4*>(dp+24) = r3;
    }
  }
}

// ---------------- Flash attention: 32x32 MFMA, 2x2 wave split (wi=q-half, wj=kv-half):
// each wave reads HALF of K and V from LDS; P stays in-register via permlane32_swap.
// LDS 24 KB: single-K + dbuf-V, r19 counted-vmcnt schedule. Cross-wj reduce at end. ----
__global__ __launch_bounds__(256, 4) void attn_bf_k(const unsigned short* __restrict__ T,
                                                    const unsigned short* __restrict__ V,
                                                    unsigned short* __restrict__ attT){
  __shared__ __align__(16) unsigned short KT[64*64];
  __shared__ __align__(16) unsigned short Vt[2][64*64];
  int tid = threadIdx.x;
  // XCD swizzle: all 16 n0-blocks of a head share id%8 (same XCD)
  int id = blockIdx.x;
  int bh = (id >> 7) * 8 + (id & 7);
  int n0 = ((id >> 3) & 15) * 64;
  int b = bh >> 3, h = bh & 7;
  int wid = tid >> 6;
  int wi = wid >> 1, wj = wid & 1;     // q-block, kv-block
  int l = tid & 63;
  int l31 = l & 31, h5 = (l >> 5) & 1;
  const unsigned short* Tb = T + ((size_t)b << 20);
  int qrow = n0 + 32*wi + l31;
  // Q B-fragments: 4 k-chunks of 16 channels (col=q=l31, k=8*h5+e)
  bf16x8 qf[4];
  #pragma unroll
  for(int kc = 0; kc < 4; kc++)
    qf[kc] = *reinterpret_cast<const bf16x8*>(Tb + (size_t)qrow*1024 + h*64 + 16*kc + 8*h5);
  f32x16 accs[2];
  #pragma unroll
  for(int r = 0; r < 16; r++){ accs[0][r] = 0.f; accs[1][r] = 0.f; }
  float l_part = 0.f;
  const unsigned short* kg = Tb + 512 + h*64;
  const unsigned short* vg = V + ((size_t)(b*512 + h*64))*1024;
  int swz  = (((l & 7) << 3) ^ ((l >> 3) << 3));
  const unsigned short* ksrc = kg + (size_t)(wid*16 + (l>>3))*1024 + swz;
  const unsigned short* vsrc = vg + (size_t)(wid*16 + (l>>3))*1024 + swz;
  int rsw = (l & 7) << 3;              // frag-read swizzle: row&7 = l31&7 = l&7
  // prologue: stage K(0), V(0)
  {
    unsigned short* kb = &KT[wid*16*64];
    unsigned short* vb = &Vt[0][wid*16*64];
    gl_lds16(ksrc,            kb);
    gl_lds16(ksrc + 8*1024,   kb + 8*64);
    gl_lds16(vsrc,            vb);
    gl_lds16(vsrc + 8*1024,   vb + 8*64);
  }
  __syncthreads();
  for(int t = 0; t < 16; t++){
    int buf = t & 1;
    // QK^T: S_local[kv 0..31][q] = sum_ch K[32wj+kv][ch] * Q[ch][q]
    f32x16 sf;
    #pragma unroll
    for(int r = 0; r < 16; r++) sf[r] = 0.f;
    #pragma unroll
    for(int kc = 0; kc < 4; kc++){
      bf16x8 a = *reinterpret_cast<const bf16x8*>(
          &KT[(32*wj + l31)*64 + ((16*kc + 8*h5) ^ rsw)]);
      sf = MFMA32(a, qf[kc], sf);
    }
    if(t < 15){
      // barrier A: all waves done reading KT -> safe to overwrite
      __builtin_amdgcn_sched_barrier(0);
      __builtin_amdgcn_s_barrier();
      __builtin_amdgcn_sched_barrier(0);
      int m1 = (t + 1) * 64;
      unsigned short* kb = &KT[wid*16*64];
      unsigned short* vb = &Vt[buf^1][wid*16*64];
      gl_lds16(ksrc + (size_t)m1*1024,          kb);
      gl_lds16(ksrc + (size_t)(m1+8)*1024,      kb + 8*64);
      gl_lds16(vsrc + m1,                       vb);
      gl_lds16(vsrc + 8*1024 + m1,              vb + 8*64);
    }
    // softmax: p = exp2(s); lane covers 16 of its wave's 32 kv rows for col q=l31
    float p[16];
    #pragma unroll
    for(int r = 0; r < 16; r++){ p[r] = EXP2(sf[r]); l_part += p[r]; }
    // pack row-pairs: u[j] = rows {8*(j>>1) + 2*(j&1) + 4h5, +1} of col q
    unsigned int u[8];
    #pragma unroll
    for(int j = 0; j < 8; j++)
      u[j] = pk2n(p[4*(j>>1) + 2*(j&1)], p[4*(j>>1) + 2*(j&1) + 1]);
    // PV B-frags via half-swap: chunk c uses swap(u[4c],u[4c+2]), swap(u[4c+1],u[4c+3])
    union { unsigned int w[4]; bf16x8 v; } pb[2];
    #pragma unroll
    for(int c = 0; c < 2; c++){
      unsigned int x0 = u[4*c],     y0 = u[4*c+2];
      unsigned int x1 = u[4*c + 1], y1 = u[4*c+3];
      plswap(x0, y0);
      plswap(x1, y1);
      pb[c].w[0] = x0; pb[c].w[1] = x1; pb[c].w[2] = y0; pb[c].w[3] = y1;
    }
    // retire V(t) (keep K/V(t+1) in flight)
    if(t < 15){ asm volatile("s_waitcnt vmcnt(4)" ::: "memory"); }
    else      { asm volatile("s_waitcnt vmcnt(0)" ::: "memory"); }
    __builtin_amdgcn_sched_barrier(0);
    // PV: out[ch][q] += V[ch][32wj+16c+k] * P_local[16c+k][q]
    #pragma unroll
    for(int mb = 0; mb < 2; mb++)
      #pragma unroll
      for(int c = 0; c < 2; c++){
        bf16x8 a = *reinterpret_cast<const bf16x8*>(
            &Vt[buf][(32*mb + l31)*64 + ((32*wj + 16*c + 8*h5) ^ rsw)]);
        accs[mb] = MFMA32(a, pb[c].v, accs[mb]);
      }
    if(t < 15){
      // barrier B: K(t+1) retired in every wave; V(t+1) stays in flight
      __builtin_amdgcn_sched_barrier(0);
      asm volatile("s_waitcnt vmcnt(2)" ::: "memory");
      __builtin_amdgcn_sched_barrier(0);
      __builtin_amdgcn_s_barrier();
    }
  }
  // l over the wave's full 32-kv window (combine halves)
  l_part += __shfl_xor(l_part, 32);
  // cross-wj reduction via LDS scratch (Vt = 16 KB acc, KT = l)
  __syncthreads();
  float* accscr = reinterpret_cast<float*>(&Vt[0][0]);
  float* lscr   = reinterpret_cast<float*>(&KT[0]);
  if(wj == 1){
    #pragma unroll
    for(int mb = 0; mb < 2; mb++)
      #pragma unroll
      for(int r = 0; r < 16; r++)
        accscr[(wi*32 + mb*16 + r)*64 + l] = accs[mb][r];
    if(l < 32) lscr[wi*32 + l31] = l_part;
  }
  __syncthreads();
  if(wj == 0){
    float inv = 1.f / (l_part + lscr[wi*32 + l31]);
    unsigned short* op = attT + ((size_t)(b*1024 + qrow))*512 + h*64;
    #pragma unroll
    for(int mb = 0; mb < 2; mb++)
      #pragma unroll
      for(int g2 = 0; g2 < 4; g2++){
        float a0 = accs[mb][4*g2+0] + accscr[(wi*32 + mb*16 + 4*g2+0)*64 + l];
        float a1 = accs[mb][4*g2+1] + accscr[(wi*32 + mb*16 + 4*g2+1)*64 + l];
        float a2 = accs[mb][4*g2+2] + accscr[(wi*32 + mb*16 + 4*g2+2)*64 + l];
        float a3 = accs[mb][4*g2+3] + accscr[(wi*32 + mb*16 + 4*g2+3)*64 + l];
        uint2 pr;
        pr.x = pk2n(a0*inv, a1*inv);
        pr.y = pk2n(a2*inv, a3*inv);
        *reinterpret_cast<uint2*>(op + 32*mb + 8*g2 + 4*h5) = pr;
      }
  }
}

// ---------------- proj GEMM (bf16 A and B, BK=64 dbuf counted-vmcnt) + bias + residual ----------------
__global__ __launch_bounds__(256) void proj_mm(const unsigned short* __restrict__ A,
                                               const unsigned short* __restrict__ Bx,
                                               const float* __restrict__ bias,
                                               const float* __restrict__ resid,
                                               float* __restrict__ out){
  __shared__ __align__(16) unsigned short As[2][128*64], Bs[2][128*64];
  int tid = threadIdx.x;
  int n0 = blockIdx.x*128, o0 = blockIdx.y*128, b = blockIdx.z;
  int wid = tid >> 6, wr = wid >> 1, wc = wid & 1, ln = tid & 15, g = (tid >> 4) & 3;
  int l = tid & 63;
  int rsw = (ln & 7) << 3;
  int srow = 32*wid + (l >> 3);
  int scol = (((l & 7) ^ (l >> 3)) << 3);
  const unsigned short* Ag = A  + (size_t)(o0 + srow)*512 + scol;
  const unsigned short* Bg = Bx + ((size_t)(b*1024 + n0 + srow))*512 + scol;
  f32x4 acc[4][4] = {};
  #pragma unroll
  for(int c = 0; c < 4; c++){
    gl_lds16(Ag + (size_t)(8*c)*512, &As[0][(32*wid + 8*c)*64]);
    gl_lds16(Bg + (size_t)(8*c)*512, &Bs[0][(32*wid + 8*c)*64]);
  }
  for(int t = 0; t < 8; t++){
    int buf = t & 1;
    if(t < 7){
      int k1 = (t + 1) * 64;
      #pragma unroll
      for(int c = 0; c < 4; c++){
        gl_lds16(Ag + (size_t)(8*c)*512 + k1, &As[buf^1][(32*wid + 8*c)*64]);
        gl_lds16(Bg + (size_t)(8*c)*512 + k1, &Bs[buf^1][(32*wid + 8*c)*64]);
      }
      asm volatile("s_waitcnt vmcnt(8)" ::: "memory");
    } else {
      asm volatile("s_waitcnt vmcnt(0)" ::: "memory");
    }
    __builtin_amdgcn_sched_barrier(0);
    __builtin_amdgcn_s_barrier();
    __builtin_amdgcn_sched_barrier(0);
    #pragma unroll
    for(int kh = 0; kh < 2; kh++){
      int ro = (kh*32 + 8*g) ^ rsw;
      bf16x8 af[4], bfv[4];
      #pragma unroll
      for(int mf = 0; mf < 4; mf++)
        af[mf] = *reinterpret_cast<const bf16x8*>(&As[buf][(wr*64 + 16*mf + ln)*64 + ro]);
      #pragma unroll
      for(int nf = 0; nf < 4; nf++)
        bfv[nf] = *reinterpret_cast<const bf16x8*>(&Bs[buf][(wc*64 + 16*nf + ln)*64 + ro]);
      #pragma unroll
      for(int mf = 0; mf < 4; mf++)
        #pragma unroll
        for(int nf = 0; nf < 4; nf++)
          acc[mf][nf] = MFMA16(af[mf], bfv[nf], acc[mf][nf]);
    }
    __builtin_amdgcn_sched_barrier(0);
    __builtin_amdgcn_s_barrier();
  }
  #pragma unroll
  for(int mf = 0; mf < 4; mf++)
    #pragma unroll
    for(int r = 0; r < 4; r++){
      int o = o0 + wr*64 + 16*mf + 4*g + r;
      float bo = bias[o];
      #pragma unroll
      for(int nf = 0; nf < 4; nf++){
        int n = n0 + wc*64 + 16*nf + ln;
        size_t off = ((size_t)(b*512 + o))*1024 + n;
        out[off] = acc[mf][nf][r] + bo + resid[off];
      }
    }
}

extern "C" void kernel_launch(void* const* d_in, const int* in_sizes, int n_in,
                              void* d_out, int out_size, void* d_ws, size_t ws_size,
                              hipStream_t stream){
  const float* x     = (const float*)d_in[0];
  const float* gnw   = (const float*)d_in[1];
  const float* gnb   = (const float*)d_in[2];
  const float* qkvw  = (const float*)d_in[3];
  const float* qkvb  = (const float*)d_in[4];
  const float* projw = (const float*)d_in[5];
  const float* projb = (const float*)d_in[6];
  float* out = (float*)d_out;

  char* w = (char*)d_ws;
  unsigned short* wqb = (unsigned short*)w;  w += (size_t)1536*512*2;
  unsigned short* wpb = (unsigned short*)w;  w += (size_t)512*512*2;
  unsigned short* xnT = (unsigned short*)w;  w += (size_t)16*1024*512*2;
  unsigned short* Tqk = (unsigned short*)w;  w += (size_t)16*1024*1024*2;
  unsigned short* Vb  = (unsigned short*)w;  w += (size_t)16*512*1024*2;
  unsigned short* attT = (unsigned short*)w; w += (size_t)16*1024*512*2;

  hipLaunchKernelGGL(pre_k, dim3(384), dim3(512), 0, stream,
                     x, gnw, gnb, xnT, qkvw, projw,
                     (unsigned int*)wqb, (unsigned int*)wpb);
  hipLaunchKernelGGL(qkv_mm, dim3(8, 12, 16), dim3(256), 0, stream, wqb, xnT, qkvb, Tqk, Vb);
  hipLaunchKernelGGL(attn_bf_k, dim3(2048), dim3(256), 0, stream, Tqk, Vb, attT);
  hipLaunchKernelGGL(proj_mm, dim3(8, 4, 16), dim3(256), 0, stream, wpb, attT, projb, x, out);
}